// Round 1
// baseline (1503.854 us; speedup 1.0000x reference)
//
#include <hip/hip_runtime.h>
#include <hip/hip_bf16.h>
#include <math.h>

#define B_    2
#define T_    2048
#define HID_  1024
#define H_    16
#define HKV_  4
#define D_    64
#define GLR_  16
#define NTOK  (B_*T_)        // 4096
#define KVD   (HKV_*D_)      // 256
#define QD    (H_*D_)        // 1024
#define CHUNK 64
#define NC    (T_/CHUNK)     // 32
#define SCALE 0.125f         // D^-0.5
#define EPS_  1e-6f

// ---------------- generic f32 GEMM: C = act(A[M,K] @ B[K,N]) ----------------
template<bool RELU>
__global__ __launch_bounds__(256) void gemm_f32(const float* __restrict__ A,
                                                const float* __restrict__ Bm,
                                                float* __restrict__ C,
                                                int M, int N, int K) {
  constexpr int BM = 64, BN = 64, BK = 16, TM = 4, TN = 4;
  __shared__ float As[BK][BM + 1];
  __shared__ float Bs[BK][BN + 1];
  const int tx = threadIdx.x & 15;        // 16 cols of threads
  const int ty = threadIdx.x >> 4;        // 16 rows of threads
  const int rowBase = blockIdx.y * BM, colBase = blockIdx.x * BN;
  float acc[TM][TN] = {};
  for (int k0 = 0; k0 < K; k0 += BK) {
    for (int idx = threadIdx.x; idx < BM * BK; idx += 256) {
      int m = idx >> 4, kk = idx & 15;
      int gm = rowBase + m;
      As[kk][m] = (gm < M) ? A[(size_t)gm * K + k0 + kk] : 0.f;
    }
    for (int idx = threadIdx.x; idx < BK * BN; idx += 256) {
      int kk = idx >> 6, n = idx & 63;
      int gn = colBase + n;
      Bs[kk][n] = (gn < N) ? Bm[(size_t)(k0 + kk) * N + gn] : 0.f;
    }
    __syncthreads();
#pragma unroll
    for (int kk = 0; kk < BK; ++kk) {
      float ra[TM], rb[TN];
#pragma unroll
      for (int i = 0; i < TM; ++i) ra[i] = As[kk][ty * TM + i];
#pragma unroll
      for (int j = 0; j < TN; ++j) rb[j] = Bs[kk][tx * TN + j];
#pragma unroll
      for (int i = 0; i < TM; ++i)
#pragma unroll
        for (int j = 0; j < TN; ++j) acc[i][j] += ra[i] * rb[j];
    }
    __syncthreads();
  }
#pragma unroll
  for (int i = 0; i < TM; ++i) {
    int gm = rowBase + ty * TM + i;
    if (gm >= M) continue;
#pragma unroll
    for (int j = 0; j < TN; ++j) {
      int gn = colBase + tx * TN + j;
      if (gn >= N) continue;
      float val = acc[i][j];
      if (RELU) val = fmaxf(val, 0.f);
      C[(size_t)gm * N + gn] = val;
    }
  }
}

// ---------------- gate: g = logsigmoid(gt @ Wg2 + bg2) / 16 ----------------
__global__ __launch_bounds__(256) void gate_kernel(const float* __restrict__ gt,
                                                   const float* __restrict__ Wg2,
                                                   const float* __restrict__ bg2,
                                                   float* __restrict__ g) {
  __shared__ float row[GLR_];
  int n = blockIdx.x;
  if (threadIdx.x < GLR_) row[threadIdx.x] = gt[(size_t)n * GLR_ + threadIdx.x];
  __syncthreads();
  int col = threadIdx.x;  // 0..255
  float acc = bg2[col];
#pragma unroll
  for (int r = 0; r < GLR_; ++r) acc += row[r] * Wg2[r * KVD + col];
  // stable log_sigmoid
  float ls = fminf(acc, 0.f) - log1pf(expf(-fabsf(acc)));
  g[(size_t)n * KVD + col] = ls * (1.0f / 16.0f);
}

// ------------- per-chunk inclusive cumsum of log-decay over t --------------
// bc layout: [b*HKV+j][t_global][d]
__global__ void cumsum_kernel(const float* __restrict__ g, float* __restrict__ bc) {
  int blk = blockIdx.x;             // (b*HKV+j)*NC + c
  int c = blk % NC, gj = blk / NC;
  int b = gj / HKV_, j = gj % HKV_;
  int d = threadIdx.x;              // 0..63
  size_t gbase = ((size_t)(b * T_ + c * CHUNK)) * KVD + j * D_ + d;
  size_t obase = ((size_t)gj * T_ + c * CHUNK) * D_ + d;
  float run = 0.f;
  for (int t = 0; t < CHUNK; ++t) {
    run += g[gbase + (size_t)t * KVD];
    bc[obase + (size_t)t * D_] = run;
  }
}

// ------------- sequential chunk-state scan (8 groups, 32 steps) -------------
// Sb layout: [gj][c][i][jv]  (state at chunk START)
__global__ __launch_bounds__(256) void gla_scan(const float* __restrict__ k,
                                                const float* __restrict__ v,
                                                const float* __restrict__ bc,
                                                float* __restrict__ Sb) {
  __shared__ float ks[CHUNK][D_ + 1];
  __shared__ float vs[CHUNK][D_ + 1];
  __shared__ float bs[CHUNK][D_ + 1];
  int gj = blockIdx.x;              // b*HKV+j
  int b = gj >> 2, j = gj & 3;
  int i = threadIdx.x >> 2;         // state row (k-dim)
  int jv0 = (threadIdx.x & 3) * 16; // state col group (v-dim)
  float S[16];
#pragma unroll
  for (int l = 0; l < 16; ++l) S[l] = 0.f;
  for (int c = 0; c < NC; ++c) {
    size_t sbase = ((size_t)gj * NC + c) * D_ * D_ + (size_t)i * D_ + jv0;
#pragma unroll
    for (int l = 0; l < 16; ++l) Sb[sbase + l] = S[l];  // state BEFORE chunk
    size_t kb = ((size_t)(b * T_ + c * CHUNK)) * KVD + j * D_;
    size_t bb = ((size_t)gj * T_ + c * CHUNK) * D_;
    for (int idx = threadIdx.x; idx < CHUNK * D_; idx += 256) {
      int t = idx >> 6, col = idx & 63;
      ks[t][col] = k[kb + (size_t)t * KVD + col];
      vs[t][col] = v[kb + (size_t)t * KVD + col];
      bs[t][col] = bc[bb + idx];
    }
    __syncthreads();
    // k' = k * exp(G - b_t)
    for (int idx = threadIdx.x; idx < CHUNK * D_; idx += 256) {
      int t = idx >> 6, col = idx & 63;
      ks[t][col] *= expf(bs[CHUNK - 1][col] - bs[t][col]);
    }
    __syncthreads();
    float eg = expf(bs[CHUNK - 1][i]);
#pragma unroll
    for (int l = 0; l < 16; ++l) S[l] *= eg;
    for (int t = 0; t < CHUNK; ++t) {
      float kti = ks[t][i];
#pragma unroll
      for (int l = 0; l < 16; ++l) S[l] += kti * vs[t][jv0 + l];
    }
    __syncthreads();
  }
}

// ---------------- per-chunk output (fully parallel, 1024 blocks) ------------
__global__ __launch_bounds__(256) void gla_out(const float* __restrict__ q,
                                               const float* __restrict__ k,
                                               const float* __restrict__ v,
                                               const float* __restrict__ bc,
                                               const float* __restrict__ Sb,
                                               float* __restrict__ ob) {
  __shared__ float qe[CHUNK][D_ + 1];   // q * exp(b) * scale
  __shared__ float ke[CHUNK][D_ + 1];   // k * exp(-b)
  __shared__ float vsh[CHUNK][D_ + 1];
  __shared__ float Ss[D_][D_ + 1];      // chunk-start state
  __shared__ float Ash[CHUNK][CHUNK + 1];
  int blk = blockIdx.x;                 // (b*H + h)*NC + c
  int c = blk % NC, bh = blk / NC;
  int b = bh / H_, h = bh % H_;
  int j = h >> 2, gj = b * HKV_ + j;
  size_t nb = (size_t)(b * T_ + c * CHUNK);
  size_t bb = ((size_t)gj * T_ + c * CHUNK) * D_;
  size_t sbase = ((size_t)gj * NC + c) * D_ * D_;
  for (int idx = threadIdx.x; idx < CHUNK * D_; idx += 256) {
    int t = idx >> 6, col = idx & 63;
    float bv = bc[bb + idx];
    qe[t][col]  = q[(nb + t) * QD + h * D_ + col] * expf(bv) * SCALE;
    ke[t][col]  = k[(nb + t) * KVD + j * D_ + col] * expf(-bv);
    vsh[t][col] = v[(nb + t) * KVD + j * D_ + col];
    Ss[t][col]  = Sb[sbase + idx];
  }
  __syncthreads();
  {
    int t = threadIdx.x >> 2, s0 = (threadIdx.x & 3) * 16;
#pragma unroll
    for (int l = 0; l < 16; ++l) {
      int s = s0 + l;
      float a = 0.f;
      if (s <= t) {
        for (int i2 = 0; i2 < D_; ++i2) a += qe[t][i2] * ke[s][i2];
      }
      Ash[t][s] = a;
    }
  }
  __syncthreads();
  {
    int t = threadIdx.x >> 2, jv0 = (threadIdx.x & 3) * 16;
    float o[16];
#pragma unroll
    for (int l = 0; l < 16; ++l) o[l] = 0.f;
    for (int i2 = 0; i2 < D_; ++i2) {
      float qv = qe[t][i2];
#pragma unroll
      for (int l = 0; l < 16; ++l) o[l] += qv * Ss[i2][jv0 + l];
    }
    for (int s = 0; s < CHUNK; ++s) {       // Ash[t][s]=0 for s>t
      float av = Ash[t][s];
#pragma unroll
      for (int l = 0; l < 16; ++l) o[l] += av * vsh[s][jv0 + l];
    }
    size_t obase = (nb + t) * QD + h * D_ + jv0;
#pragma unroll
    for (int l = 0; l < 16; ++l) ob[obase + l] = o[l];
  }
}

// ---------------- per-head RMSNorm over D=64 (one wave per row) -------------
__global__ __launch_bounds__(256) void rms_kernel(float* __restrict__ ob,
                                                  const float* __restrict__ gw) {
  int row = blockIdx.x * 4 + (threadIdx.x >> 6);   // n*H + h
  int lane = threadIdx.x & 63;
  size_t base = (size_t)row * D_;
  float x = ob[base + lane];
  float ss = x * x;
#pragma unroll
  for (int off = 32; off >= 1; off >>= 1) ss += __shfl_xor(ss, off, 64);
  float inv = rsqrtf(ss * (1.0f / D_) + EPS_);
  ob[base + lane] = gw[lane] * x * inv;
}

extern "C" void kernel_launch(void* const* d_in, const int* in_sizes, int n_in,
                              void* d_out, int out_size, void* d_ws, size_t ws_size,
                              hipStream_t stream) {
  const float* h   = (const float*)d_in[0];
  const float* Wq  = (const float*)d_in[1];
  const float* Wk  = (const float*)d_in[2];
  const float* Wv  = (const float*)d_in[3];
  const float* Wo  = (const float*)d_in[4];
  const float* Wg1 = (const float*)d_in[5];
  const float* Wg2 = (const float*)d_in[6];
  const float* bg2 = (const float*)d_in[7];
  const float* gw  = (const float*)d_in[8];
  float* out = (float*)d_out;

  float* q  = (float*)d_ws;                          // [4096,1024]
  float* k  = q  + (size_t)NTOK * QD;                // [4096,256]
  float* v  = k  + (size_t)NTOK * KVD;               // [4096,256]
  float* g  = v  + (size_t)NTOK * KVD;               // [4096,256]
  float* gt = g  + (size_t)NTOK * KVD;               // [4096,16]
  float* bc = gt + (size_t)NTOK * GLR_;              // [8,2048,64]
  float* Sb = bc + (size_t)B_ * HKV_ * T_ * D_;      // [8,32,64,64]
  float* ob = Sb + (size_t)B_ * HKV_ * NC * D_ * D_; // [4096,1024]

  dim3 blk(256);
  // projections
  gemm_f32<true ><<<dim3(QD / 64,  NTOK / 64), blk, 0, stream>>>(h, Wq, q, NTOK, QD, HID_);
  gemm_f32<true ><<<dim3(KVD / 64, NTOK / 64), blk, 0, stream>>>(h, Wk, k, NTOK, KVD, HID_);
  gemm_f32<false><<<dim3(KVD / 64, NTOK / 64), blk, 0, stream>>>(h, Wv, v, NTOK, KVD, HID_);
  gemm_f32<false><<<dim3(1,        NTOK / 64), blk, 0, stream>>>(h, Wg1, gt, NTOK, GLR_, HID_);
  // gate
  gate_kernel<<<NTOK, blk, 0, stream>>>(gt, Wg2, bg2, g);
  // decay cumsum per chunk
  cumsum_kernel<<<B_ * HKV_ * NC, dim3(64), 0, stream>>>(g, bc);
  // chunk-state scan (sequential over 32 chunks, 8 groups)
  gla_scan<<<B_ * HKV_, blk, 0, stream>>>(k, v, bc, Sb);
  // per-chunk outputs
  gla_out<<<B_ * H_ * NC, blk, 0, stream>>>(q, k, v, bc, Sb, ob);
  // RMSNorm
  rms_kernel<<<NTOK * H_ / 4, blk, 0, stream>>>(ob, gw);
  // output projection
  gemm_f32<false><<<dim3(HID_ / 64, NTOK / 64), blk, 0, stream>>>(ob, Wo, out, NTOK, HID_, HID_);
}

// Round 4
// 491.204 us; speedup vs baseline: 3.0616x; 3.0616x over previous
//
#include <hip/hip_runtime.h>
#include <hip/hip_bf16.h>
#include <math.h>

#define B_    2
#define T_    2048
#define HID_  1024
#define H_    16
#define HKV_  4
#define D_    64
#define GLR_  16
#define NTOK  (B_*T_)        // 4096
#define KVD   (HKV_*D_)      // 256
#define KVSTR 512            // fused kv row stride (k:0..255, v:256..511)
#define QD    (H_*D_)        // 1024
#define CHUNK 64
#define NC    (T_/CHUNK)     // 32
#define SCALE 0.125f         // D^-0.5
#define EPS_  1e-6f

typedef __attribute__((ext_vector_type(8))) short short8;
typedef __attribute__((ext_vector_type(4))) float f32x4;

__device__ __forceinline__ ushort f2b(float f) {
  __hip_bfloat16 h = __float2bfloat16(f);
  return *reinterpret_cast<ushort*>(&h);
}

// ---------------- f32 -> bf16 cast (vectorized) ----------------
__global__ __launch_bounds__(256) void cast_bf16_kernel(const float* __restrict__ in,
                                                        ushort* __restrict__ out, int n4) {
  int i = blockIdx.x * 256 + threadIdx.x;
  if (i >= n4) return;
  float4 v = *(const float4*)(in + (size_t)i * 4);
  ushort4 o;
  o.x = f2b(v.x); o.y = f2b(v.y); o.z = f2b(v.z); o.w = f2b(v.w);
  *(ushort4*)(out + (size_t)i * 4) = o;
}

// ------------- W[K][N] f32 -> Wt[N][K] bf16 (64x64 LDS tile) -------------
__global__ __launch_bounds__(256) void transpose_cast(const float* __restrict__ W,
                                                      ushort* __restrict__ Wt,
                                                      int K, int N) {
  __shared__ ushort tile[64][65];
  int n0 = blockIdx.x * 64, k0 = blockIdx.y * 64;
  for (int idx = threadIdx.x; idx < 64 * 64; idx += 256) {
    int r = idx >> 6, c = idx & 63;                  // r: k-offset, c: n-offset
    tile[c][r] = f2b(W[(size_t)(k0 + r) * N + n0 + c]);
  }
  __syncthreads();
  for (int idx = threadIdx.x; idx < 64 * 64; idx += 256) {
    int r = idx >> 6, c = idx & 63;                  // r: n-offset, c: k-offset
    Wt[(size_t)(n0 + r) * K + k0 + c] = tile[r][c];
  }
}

// -------- bf16 MFMA GEMM: C[M,N] = act(A[M,K] @ Bt[N,K]^T), f32 out --------
// 128x128 tile, BK=32, 4 waves (2x2), each wave 64x64 via 4x4 16x16x32 frags.
template<bool RELU>
__global__ __launch_bounds__(256) void gemm_bf16_mfma(const ushort* __restrict__ A,
                                                      const ushort* __restrict__ Bt,
                                                      float* __restrict__ C,
                                                      int M, int N, int K) {
  __shared__ ushort As[128][40];   // +8 pad: row stride 80B = 5x16B (aligned, spread banks)
  __shared__ ushort Bs[128][40];
  const int t = threadIdx.x;
  const int rowBase = blockIdx.y * 128, colBase = blockIdx.x * 128;
  const int lane = t & 63, w = t >> 6;
  const int wr = w >> 1, wc = w & 1;
  const int lrow = lane & 15, hi = lane >> 4;
  f32x4 acc[4][4];
#pragma unroll
  for (int mi = 0; mi < 4; ++mi)
#pragma unroll
    for (int ni = 0; ni < 4; ++ni) acc[mi][ni] = (f32x4){0.f, 0.f, 0.f, 0.f};

  for (int k0 = 0; k0 < K; k0 += 32) {
#pragma unroll
    for (int l = 0; l < 2; ++l) {
      int idx = t + (l << 8);                 // 0..511
      int row = idx >> 2, ch = (idx & 3) << 3;
      *(short8*)&As[row][ch] = *(const short8*)&A[(size_t)(rowBase + row) * K + k0 + ch];
      *(short8*)&Bs[row][ch] = *(const short8*)&Bt[(size_t)(colBase + row) * K + k0 + ch];
    }
    __syncthreads();
    short8 af[4], bf[4];
#pragma unroll
    for (int mi = 0; mi < 4; ++mi)
      af[mi] = *(const short8*)&As[wr * 64 + mi * 16 + lrow][hi * 8];
#pragma unroll
    for (int ni = 0; ni < 4; ++ni)
      bf[ni] = *(const short8*)&Bs[wc * 64 + ni * 16 + lrow][hi * 8];
#pragma unroll
    for (int mi = 0; mi < 4; ++mi)
#pragma unroll
      for (int ni = 0; ni < 4; ++ni)
        acc[mi][ni] = __builtin_amdgcn_mfma_f32_16x16x32_bf16(af[mi], bf[ni], acc[mi][ni], 0, 0, 0);
    __syncthreads();
  }
#pragma unroll
  for (int mi = 0; mi < 4; ++mi)
#pragma unroll
    for (int ni = 0; ni < 4; ++ni)
#pragma unroll
      for (int r = 0; r < 4; ++r) {
        int gm = rowBase + wr * 64 + mi * 16 + hi * 4 + r;
        int gn = colBase + wc * 64 + ni * 16 + lrow;
        float val = acc[mi][ni][r];
        if (RELU) val = fmaxf(val, 0.f);
        C[(size_t)gm * N + gn] = val;
      }
}

// ---------------- generic f32 GEMM (kept for Wg1, N=16) ----------------
template<bool RELU>
__global__ __launch_bounds__(256) void gemm_f32(const float* __restrict__ A,
                                                const float* __restrict__ Bm,
                                                float* __restrict__ C,
                                                int M, int N, int K) {
  constexpr int BM = 64, BN = 64, BK = 16, TM = 4, TN = 4;
  __shared__ float As[BK][BM + 1];
  __shared__ float Bs[BK][BN + 1];
  const int tx = threadIdx.x & 15;
  const int ty = threadIdx.x >> 4;
  const int rowBase = blockIdx.y * BM, colBase = blockIdx.x * BN;
  float acc[TM][TN] = {};
  for (int k0 = 0; k0 < K; k0 += BK) {
    for (int idx = threadIdx.x; idx < BM * BK; idx += 256) {
      int m = idx >> 4, kk = idx & 15;
      int gm = rowBase + m;
      As[kk][m] = (gm < M) ? A[(size_t)gm * K + k0 + kk] : 0.f;
    }
    for (int idx = threadIdx.x; idx < BK * BN; idx += 256) {
      int kk = idx >> 6, n = idx & 63;
      int gn = colBase + n;
      Bs[kk][n] = (gn < N) ? Bm[(size_t)(k0 + kk) * N + gn] : 0.f;
    }
    __syncthreads();
#pragma unroll
    for (int kk = 0; kk < BK; ++kk) {
      float ra[TM], rb[TN];
#pragma unroll
      for (int i = 0; i < TM; ++i) ra[i] = As[kk][ty * TM + i];
#pragma unroll
      for (int j = 0; j < TN; ++j) rb[j] = Bs[kk][tx * TN + j];
#pragma unroll
      for (int i = 0; i < TM; ++i)
#pragma unroll
        for (int j = 0; j < TN; ++j) acc[i][j] += ra[i] * rb[j];
    }
    __syncthreads();
  }
#pragma unroll
  for (int i = 0; i < TM; ++i) {
    int gm = rowBase + ty * TM + i;
    if (gm >= M) continue;
#pragma unroll
    for (int j = 0; j < TN; ++j) {
      int gn = colBase + tx * TN + j;
      if (gn >= N) continue;
      float val = acc[i][j];
      if (RELU) val = fmaxf(val, 0.f);
      C[(size_t)gm * N + gn] = val;
    }
  }
}

// ---------------- gate: g = logsigmoid(gt @ Wg2 + bg2) / 16 ----------------
__global__ __launch_bounds__(256) void gate_kernel(const float* __restrict__ gt,
                                                   const float* __restrict__ Wg2,
                                                   const float* __restrict__ bg2,
                                                   float* __restrict__ g) {
  __shared__ float row[GLR_];
  int n = blockIdx.x;
  if (threadIdx.x < GLR_) row[threadIdx.x] = gt[(size_t)n * GLR_ + threadIdx.x];
  __syncthreads();
  int col = threadIdx.x;
  float acc = bg2[col];
#pragma unroll
  for (int r = 0; r < GLR_; ++r) acc += row[r] * Wg2[r * KVD + col];
  float ls = fminf(acc, 0.f) - log1pf(expf(-fabsf(acc)));
  g[(size_t)n * KVD + col] = ls * (1.0f / 16.0f);
}

// ------------- per-chunk inclusive cumsum of log-decay over t --------------
__global__ void cumsum_kernel(const float* __restrict__ g, float* __restrict__ bc) {
  int blk = blockIdx.x;             // (b*HKV+j)*NC + c
  int c = blk % NC, gj = blk / NC;
  int b = gj / HKV_, j = gj % HKV_;
  int d = threadIdx.x;
  size_t gbase = ((size_t)(b * T_ + c * CHUNK)) * KVD + j * D_ + d;
  size_t obase = ((size_t)gj * T_ + c * CHUNK) * D_ + d;
  float run = 0.f;
  for (int t = 0; t < CHUNK; ++t) {
    run += g[gbase + (size_t)t * KVD];
    bc[obase + (size_t)t * D_] = run;
  }
}

// -------- per-chunk decayed K^T V (256 parallel blocks); relu(k) here ------
__global__ __launch_bounds__(256) void chunk_kv(const float* __restrict__ kv,
                                                const float* __restrict__ bc,
                                                float* __restrict__ M,
                                                float* __restrict__ E) {
  __shared__ float ks[CHUNK][D_ + 1];
  __shared__ float vs[CHUNK][D_ + 1];
  __shared__ float blast[D_];
  int blk = blockIdx.x;             // gj*NC + c
  int c = blk % NC, gj = blk / NC;
  int b = gj >> 2, j = gj & 3;
  size_t kb = ((size_t)(b * T_ + c * CHUNK)) * KVSTR + j * D_;
  size_t bb = ((size_t)gj * T_ + c * CHUNK) * D_;
  if (threadIdx.x < D_) blast[threadIdx.x] = bc[bb + (size_t)(CHUNK - 1) * D_ + threadIdx.x];
  __syncthreads();
  for (int idx = threadIdx.x; idx < CHUNK * D_; idx += 256) {
    int t = idx >> 6, col = idx & 63;
    float bv = bc[bb + idx];
    ks[t][col] = fmaxf(kv[kb + (size_t)t * KVSTR + col], 0.f) * expf(blast[col] - bv);
    vs[t][col] = kv[kb + (size_t)t * KVSTR + 256 + col];
  }
  __syncthreads();
  int i = threadIdx.x >> 2;
  int jv0 = (threadIdx.x & 3) * 16;
  float acc[16];
#pragma unroll
  for (int l = 0; l < 16; ++l) acc[l] = 0.f;
  for (int t = 0; t < CHUNK; ++t) {
    float kt = ks[t][i];
#pragma unroll
    for (int l = 0; l < 16; ++l) acc[l] += kt * vs[t][jv0 + l];
  }
  size_t mbase = (size_t)blk * D_ * D_ + (size_t)i * D_ + jv0;
#pragma unroll
  for (int l = 0; l < 16; ++l) M[mbase + l] = acc[l];
  if (threadIdx.x < D_) E[(size_t)blk * D_ + threadIdx.x] = expf(blast[threadIdx.x]);
}

// ---- elementwise inter-chunk scan: S_{c+1} = E_c[i]*S_c + M_c ----
__global__ __launch_bounds__(256) void state_scan(const float* __restrict__ M,
                                                  const float* __restrict__ E,
                                                  float* __restrict__ Sb) {
  int gj = blockIdx.x >> 4;
  int elem = ((blockIdx.x & 15) << 8) + threadIdx.x;
  int i = elem >> 6;
  float S = 0.f;
#pragma unroll
  for (int c = 0; c < NC; ++c) {
    size_t base = ((size_t)gj * NC + c) * (D_ * D_) + elem;
    Sb[base] = S;
    S = E[((size_t)gj * NC + c) * D_ + i] * S + M[base];
  }
}

// ---------------- per-chunk output (1024 blocks); relu(k) here -------------
__global__ __launch_bounds__(256) void gla_out(const float* __restrict__ q,
                                               const float* __restrict__ kv,
                                               const float* __restrict__ bc,
                                               const float* __restrict__ Sb,
                                               float* __restrict__ ob) {
  __shared__ float qe[CHUNK][D_ + 1];
  __shared__ float ke[CHUNK][D_ + 1];
  __shared__ float vsh[CHUNK][D_ + 1];
  __shared__ float Ss[D_][D_ + 1];
  __shared__ float Ash[CHUNK][CHUNK + 1];
  int blk = blockIdx.x;                 // (b*H + h)*NC + c
  int c = blk % NC, bh = blk / NC;
  int b = bh / H_, h = bh % H_;
  int j = h >> 2, gj = b * HKV_ + j;
  size_t nb = (size_t)(b * T_ + c * CHUNK);
  size_t bb = ((size_t)gj * T_ + c * CHUNK) * D_;
  size_t sbase = ((size_t)gj * NC + c) * D_ * D_;
  for (int idx = threadIdx.x; idx < CHUNK * D_; idx += 256) {
    int t = idx >> 6, col = idx & 63;
    float bv = bc[bb + idx];
    qe[t][col]  = q[(nb + t) * QD + h * D_ + col] * expf(bv) * SCALE;
    ke[t][col]  = fmaxf(kv[(nb + t) * KVSTR + j * D_ + col], 0.f) * expf(-bv);
    vsh[t][col] = kv[(nb + t) * KVSTR + 256 + j * D_ + col];
    Ss[t][col]  = Sb[sbase + idx];
  }
  __syncthreads();
  {
    int t = threadIdx.x >> 2, s0 = (threadIdx.x & 3) * 16;
#pragma unroll
    for (int l = 0; l < 16; ++l) {
      int s = s0 + l;
      float a = 0.f;
      if (s <= t) {
        for (int i2 = 0; i2 < D_; ++i2) a += qe[t][i2] * ke[s][i2];
      }
      Ash[t][s] = a;
    }
  }
  __syncthreads();
  {
    int t = threadIdx.x >> 2, jv0 = (threadIdx.x & 3) * 16;
    float o[16];
#pragma unroll
    for (int l = 0; l < 16; ++l) o[l] = 0.f;
    for (int i2 = 0; i2 < D_; ++i2) {
      float qv = qe[t][i2];
#pragma unroll
      for (int l = 0; l < 16; ++l) o[l] += qv * Ss[i2][jv0 + l];
    }
    for (int s = 0; s < CHUNK; ++s) {
      float av = Ash[t][s];
#pragma unroll
      for (int l = 0; l < 16; ++l) o[l] += av * vsh[s][jv0 + l];
    }
    size_t obase = (nb + t) * QD + h * D_ + jv0;
#pragma unroll
    for (int l = 0; l < 16; ++l) ob[obase + l] = o[l];
  }
}

// ------------- per-head RMSNorm over D=64; writes bf16 for Wo GEMM ---------
__global__ __launch_bounds__(256) void rms_kernel(const float* __restrict__ ob,
                                                  const float* __restrict__ gw,
                                                  ushort* __restrict__ obh) {
  int row = blockIdx.x * 4 + (threadIdx.x >> 6);
  int lane = threadIdx.x & 63;
  size_t base = (size_t)row * D_;
  float x = ob[base + lane];
  float ss = x * x;
#pragma unroll
  for (int off = 32; off >= 1; off >>= 1) ss += __shfl_xor(ss, off, 64);
  float inv = rsqrtf(ss * (1.0f / D_) + EPS_);
  obh[base + lane] = f2b(gw[lane] * x * inv);
}

extern "C" void kernel_launch(void* const* d_in, const int* in_sizes, int n_in,
                              void* d_out, int out_size, void* d_ws, size_t ws_size,
                              hipStream_t stream) {
  const float* h   = (const float*)d_in[0];
  const float* Wq  = (const float*)d_in[1];
  const float* Wk  = (const float*)d_in[2];
  const float* Wv  = (const float*)d_in[3];
  const float* Wo  = (const float*)d_in[4];
  const float* Wg1 = (const float*)d_in[5];
  const float* Wg2 = (const float*)d_in[6];
  const float* bg2 = (const float*)d_in[7];
  const float* gw  = (const float*)d_in[8];
  float* out = (float*)d_out;

  float* q   = (float*)d_ws;                          // [4096,1024] (reused as ob)
  float* kv  = q  + (size_t)NTOK * QD;                // [4096,512]
  float* g   = kv + (size_t)NTOK * KVSTR;             // [4096,256]
  float* gt  = g  + (size_t)NTOK * KVD;               // [4096,16]
  float* bc  = gt + (size_t)NTOK * GLR_;              // [8,2048,64]
  float* Sb  = bc + (size_t)B_ * HKV_ * T_ * D_;      // [8,32,64,64]
  float* Mm  = Sb + (size_t)B_ * HKV_ * NC * D_ * D_; // [8,32,64,64]
  float* E   = Mm + (size_t)B_ * HKV_ * NC * D_ * D_; // [8,32,64]
  ushort* hb   = (ushort*)(E + (size_t)B_ * HKV_ * NC * D_); // [4096,1024] bf16 (reused as obh)
  ushort* Wqt  = hb   + (size_t)NTOK * HID_;          // [1024,1024]
  ushort* Wkvt = Wqt  + (size_t)HID_ * QD;            // [512,1024]
  ushort* Wot  = Wkvt + (size_t)KVSTR * HID_;         // [1024,1024]
  float* ob = q;
  ushort* obh = hb;

  dim3 blk(256);
  // bf16 staging: cast h, transpose+cast weights
  cast_bf16_kernel<<<(NTOK * HID_ / 4 + 255) / 256, blk, 0, stream>>>(h, hb, NTOK * HID_ / 4);
  transpose_cast<<<dim3(QD / 64, HID_ / 64), blk, 0, stream>>>(Wq, Wqt, HID_, QD);
  transpose_cast<<<dim3(KVD / 64, HID_ / 64), blk, 0, stream>>>(Wk, Wkvt, HID_, KVD);
  transpose_cast<<<dim3(KVD / 64, HID_ / 64), blk, 0, stream>>>(Wv, Wkvt + (size_t)KVD * HID_, HID_, KVD);
  transpose_cast<<<dim3(HID_ / 64, QD / 64), blk, 0, stream>>>(Wo, Wot, QD, HID_);
  // projections (MFMA); k-relu deferred to consumers, v linear
  gemm_bf16_mfma<true ><<<dim3(QD / 128, NTOK / 128), blk, 0, stream>>>(hb, Wqt, q, NTOK, QD, HID_);
  gemm_bf16_mfma<false><<<dim3(KVSTR / 128, NTOK / 128), blk, 0, stream>>>(hb, Wkvt, kv, NTOK, KVSTR, HID_);
  gemm_f32<false><<<dim3(1, NTOK / 64), blk, 0, stream>>>(h, Wg1, gt, NTOK, GLR_, HID_);
  // gate + decay cumsum
  gate_kernel<<<NTOK, blk, 0, stream>>>(gt, Wg2, bg2, g);
  cumsum_kernel<<<B_ * HKV_ * NC, dim3(64), 0, stream>>>(g, bc);
  // chunked GLA
  chunk_kv<<<B_ * HKV_ * NC, blk, 0, stream>>>(kv, bc, Mm, E);
  state_scan<<<B_ * HKV_ * 16, blk, 0, stream>>>(Mm, E, Sb);
  gla_out<<<B_ * H_ * NC, blk, 0, stream>>>(q, kv, bc, Sb, ob);
  // RMSNorm (bf16 out) + output projection (MFMA)
  rms_kernel<<<NTOK * H_ / 4, blk, 0, stream>>>(ob, gw, obh);
  gemm_bf16_mfma<false><<<dim3(HID_ / 128, NTOK / 128), blk, 0, stream>>>(obh, Wot, out, NTOK, HID_, HID_);
}

// Round 5
// 335.233 us; speedup vs baseline: 4.4860x; 1.4653x over previous
//
#include <hip/hip_runtime.h>
#include <hip/hip_bf16.h>
#include <math.h>

#define B_    2
#define T_    2048
#define HID_  1024
#define H_    16
#define HKV_  4
#define D_    64
#define GLR_  16
#define NTOK  (B_*T_)        // 4096
#define KVD   (HKV_*D_)      // 256
#define KVSTR 512            // fused kv row stride (k:0..255, v:256..511)
#define QD    (H_*D_)        // 1024
#define CHUNK 64
#define NC    (T_/CHUNK)     // 32
#define SCALE 0.125f         // D^-0.5
#define EPS_  1e-6f

typedef __attribute__((ext_vector_type(8))) short short8;
typedef __attribute__((ext_vector_type(4))) float f32x4;

__device__ __forceinline__ ushort f2b(float f) {
  __hip_bfloat16 h = __float2bfloat16(f);
  return *reinterpret_cast<ushort*>(&h);
}

// ---------------- f32 -> bf16 cast (vectorized) ----------------
__global__ __launch_bounds__(256) void cast_bf16_kernel(const float* __restrict__ in,
                                                        ushort* __restrict__ out, int n4) {
  int i = blockIdx.x * 256 + threadIdx.x;
  if (i >= n4) return;
  float4 v = *(const float4*)(in + (size_t)i * 4);
  ushort4 o;
  o.x = f2b(v.x); o.y = f2b(v.y); o.z = f2b(v.z); o.w = f2b(v.w);
  *(ushort4*)(out + (size_t)i * 4) = o;
}

// ------------- W[K][N] f32 -> Wt[N][K] bf16 (64x64 LDS tile) -------------
__global__ __launch_bounds__(256) void transpose_cast(const float* __restrict__ W,
                                                      ushort* __restrict__ Wt,
                                                      int K, int N) {
  __shared__ ushort tile[64][65];
  int n0 = blockIdx.x * 64, k0 = blockIdx.y * 64;
  for (int idx = threadIdx.x; idx < 64 * 64; idx += 256) {
    int r = idx >> 6, c = idx & 63;                  // r: k-offset, c: n-offset
    tile[c][r] = f2b(W[(size_t)(k0 + r) * N + n0 + c]);
  }
  __syncthreads();
  for (int idx = threadIdx.x; idx < 64 * 64; idx += 256) {
    int r = idx >> 6, c = idx & 63;                  // r: n-offset, c: k-offset
    Wt[(size_t)(n0 + r) * K + k0 + c] = tile[r][c];
  }
}

// ------------- Wg1[1024,16] f32 -> Wg1t[16][1024] bf16 -------------
__global__ __launch_bounds__(256) void cast_wg1(const float* __restrict__ Wg1,
                                                ushort* __restrict__ Wg1t) {
  int idx = blockIdx.x * 256 + threadIdx.x;   // 0..16383
  int kk = idx >> 4, n = idx & 15;
  Wg1t[(size_t)n * HID_ + kk] = f2b(Wg1[(size_t)kk * GLR_ + n]);
}

// -------- bf16 MFMA GEMM: C[M,N] = act(A[M,K] @ Bt[N,K]^T), f32 out --------
// 128x128 tile, BK=32, 4 waves (2x2), each wave 64x64 via 4x4 16x16x32 frags.
template<bool RELU>
__global__ __launch_bounds__(256) void gemm_bf16_mfma(const ushort* __restrict__ A,
                                                      const ushort* __restrict__ Bt,
                                                      float* __restrict__ C,
                                                      int M, int N, int K) {
  __shared__ ushort As[128][40];   // +8 pad: row stride 80B = 5x16B (aligned, spread banks)
  __shared__ ushort Bs[128][40];
  const int t = threadIdx.x;
  const int rowBase = blockIdx.y * 128, colBase = blockIdx.x * 128;
  const int lane = t & 63, w = t >> 6;
  const int wr = w >> 1, wc = w & 1;
  const int lrow = lane & 15, hi = lane >> 4;
  f32x4 acc[4][4];
#pragma unroll
  for (int mi = 0; mi < 4; ++mi)
#pragma unroll
    for (int ni = 0; ni < 4; ++ni) acc[mi][ni] = (f32x4){0.f, 0.f, 0.f, 0.f};

  for (int k0 = 0; k0 < K; k0 += 32) {
#pragma unroll
    for (int l = 0; l < 2; ++l) {
      int idx = t + (l << 8);                 // 0..511
      int row = idx >> 2, ch = (idx & 3) << 3;
      *(short8*)&As[row][ch] = *(const short8*)&A[(size_t)(rowBase + row) * K + k0 + ch];
      *(short8*)&Bs[row][ch] = *(const short8*)&Bt[(size_t)(colBase + row) * K + k0 + ch];
    }
    __syncthreads();
    short8 af[4], bf[4];
#pragma unroll
    for (int mi = 0; mi < 4; ++mi)
      af[mi] = *(const short8*)&As[wr * 64 + mi * 16 + lrow][hi * 8];
#pragma unroll
    for (int ni = 0; ni < 4; ++ni)
      bf[ni] = *(const short8*)&Bs[wc * 64 + ni * 16 + lrow][hi * 8];
#pragma unroll
    for (int mi = 0; mi < 4; ++mi)
#pragma unroll
      for (int ni = 0; ni < 4; ++ni)
        acc[mi][ni] = __builtin_amdgcn_mfma_f32_16x16x32_bf16(af[mi], bf[ni], acc[mi][ni], 0, 0, 0);
    __syncthreads();
  }
#pragma unroll
  for (int mi = 0; mi < 4; ++mi)
#pragma unroll
    for (int ni = 0; ni < 4; ++ni)
#pragma unroll
      for (int r = 0; r < 4; ++r) {
        int gm = rowBase + wr * 64 + mi * 16 + hi * 4 + r;
        int gn = colBase + wc * 64 + ni * 16 + lrow;
        float val = acc[mi][ni][r];
        if (RELU) val = fmaxf(val, 0.f);
        C[(size_t)gm * N + gn] = val;
      }
}

// ------ fused gate: gt = h@Wg1 (MFMA, K-split), g = logsig(gt@Wg2+bg2)/16 ---
// 256 blocks x 256 threads; block handles 16 tokens.
__global__ __launch_bounds__(256) void gate_fused(const ushort* __restrict__ hb,
                                                  const ushort* __restrict__ Wg1t,
                                                  const float* __restrict__ Wg2,
                                                  const float* __restrict__ bg2,
                                                  float* __restrict__ g) {
  __shared__ float part[4][16][17];
  __shared__ float gts[16][17];
  const int t = threadIdx.x, lane = t & 63, w = t >> 6;
  const int lrow = lane & 15, hi = lane >> 4;
  const int nb0 = blockIdx.x * 16;
  // stage 1: gt[16 tok][16 n] via MFMA, wave w covers K slice [w*256,(w+1)*256)
  f32x4 acc = (f32x4){0.f, 0.f, 0.f, 0.f};
  const int kb = w * 256;
#pragma unroll
  for (int kk = 0; kk < 8; ++kk) {
    int k0 = kb + kk * 32 + hi * 8;
    short8 a = *(const short8*)&hb[(size_t)(nb0 + lrow) * HID_ + k0];
    short8 b = *(const short8*)&Wg1t[(size_t)lrow * HID_ + k0];
    acc = __builtin_amdgcn_mfma_f32_16x16x32_bf16(a, b, acc, 0, 0, 0);
  }
#pragma unroll
  for (int r = 0; r < 4; ++r) part[w][hi * 4 + r][lrow] = acc[r];  // [tok][n]
  __syncthreads();
  {
    int tok = t >> 4, n = t & 15;
    gts[tok][n] = part[0][tok][n] + part[1][tok][n] + part[2][tok][n] + part[3][tok][n];
  }
  __syncthreads();
  // stage 2: thread = column c; 16 tokens
  const int c = t;
  const float bias = bg2[c];
#pragma unroll 4
  for (int tok = 0; tok < 16; ++tok) {
    float acc2 = bias;
#pragma unroll
    for (int r = 0; r < GLR_; ++r) acc2 += gts[tok][r] * Wg2[r * KVD + c];
    float ls = fminf(acc2, 0.f) - log1pf(expf(-fabsf(acc2)));
    g[(size_t)(nb0 + tok) * KVD + c] = ls * (1.0f / 16.0f);
  }
}

// ------------- per-chunk inclusive cumsum of log-decay over t --------------
__global__ void cumsum_kernel(const float* __restrict__ g, float* __restrict__ bc) {
  int blk = blockIdx.x;             // (b*HKV+j)*NC + c
  int c = blk % NC, gj = blk / NC;
  int b = gj / HKV_, j = gj % HKV_;
  int d = threadIdx.x;
  size_t gbase = ((size_t)(b * T_ + c * CHUNK)) * KVD + j * D_ + d;
  size_t obase = ((size_t)gj * T_ + c * CHUNK) * D_ + d;
  float run = 0.f;
  for (int t = 0; t < CHUNK; ++t) {
    run += g[gbase + (size_t)t * KVD];
    bc[obase + (size_t)t * D_] = run;
  }
}

// -------- per-chunk decayed K^T V (256 parallel blocks); relu(k) here ------
__global__ __launch_bounds__(256) void chunk_kv(const float* __restrict__ kv,
                                                const float* __restrict__ bc,
                                                float* __restrict__ M,
                                                float* __restrict__ E) {
  __shared__ float ks[CHUNK][D_ + 1];
  __shared__ float vs[CHUNK][D_ + 1];
  __shared__ float blast[D_];
  int blk = blockIdx.x;             // gj*NC + c
  int c = blk % NC, gj = blk / NC;
  int b = gj >> 2, j = gj & 3;
  size_t kb = ((size_t)(b * T_ + c * CHUNK)) * KVSTR + j * D_;
  size_t bb = ((size_t)gj * T_ + c * CHUNK) * D_;
  if (threadIdx.x < D_) blast[threadIdx.x] = bc[bb + (size_t)(CHUNK - 1) * D_ + threadIdx.x];
  __syncthreads();
  for (int idx = threadIdx.x; idx < CHUNK * D_; idx += 256) {
    int t = idx >> 6, col = idx & 63;
    float bv = bc[bb + idx];
    ks[t][col] = fmaxf(kv[kb + (size_t)t * KVSTR + col], 0.f) * expf(blast[col] - bv);
    vs[t][col] = kv[kb + (size_t)t * KVSTR + 256 + col];
  }
  __syncthreads();
  int i = threadIdx.x >> 2;
  int jv0 = (threadIdx.x & 3) * 16;
  float acc[16];
#pragma unroll
  for (int l = 0; l < 16; ++l) acc[l] = 0.f;
  for (int t = 0; t < CHUNK; ++t) {
    float kt = ks[t][i];
#pragma unroll
    for (int l = 0; l < 16; ++l) acc[l] += kt * vs[t][jv0 + l];
  }
  size_t mbase = (size_t)blk * D_ * D_ + (size_t)i * D_ + jv0;
#pragma unroll
  for (int l = 0; l < 16; ++l) M[mbase + l] = acc[l];
  if (threadIdx.x < D_) E[(size_t)blk * D_ + threadIdx.x] = expf(blast[threadIdx.x]);
}

// ---- elementwise inter-chunk scan: S_{c+1} = E_c[i]*S_c + M_c ----
__global__ __launch_bounds__(256) void state_scan(const float* __restrict__ M,
                                                  const float* __restrict__ E,
                                                  float* __restrict__ Sb) {
  int gj = blockIdx.x >> 4;
  int elem = ((blockIdx.x & 15) << 8) + threadIdx.x;
  int i = elem >> 6;
  float S = 0.f;
#pragma unroll
  for (int c = 0; c < NC; ++c) {
    size_t base = ((size_t)gj * NC + c) * (D_ * D_) + elem;
    Sb[base] = S;
    S = E[((size_t)gj * NC + c) * D_ + i] * S + M[base];
  }
}

// ---------------- per-chunk output (1024 blocks); relu(k) here -------------
__global__ __launch_bounds__(256) void gla_out(const float* __restrict__ q,
                                               const float* __restrict__ kv,
                                               const float* __restrict__ bc,
                                               const float* __restrict__ Sb,
                                               float* __restrict__ ob) {
  __shared__ float qe[CHUNK][D_ + 1];
  __shared__ float ke[CHUNK][D_ + 1];
  __shared__ float vsh[CHUNK][D_ + 1];
  __shared__ float Ss[D_][D_ + 1];
  __shared__ float Ash[CHUNK][CHUNK + 1];
  int blk = blockIdx.x;                 // (b*H + h)*NC + c
  int c = blk % NC, bh = blk / NC;
  int b = bh / H_, h = bh % H_;
  int j = h >> 2, gj = b * HKV_ + j;
  size_t nb = (size_t)(b * T_ + c * CHUNK);
  size_t bb = ((size_t)gj * T_ + c * CHUNK) * D_;
  size_t sbase = ((size_t)gj * NC + c) * D_ * D_;
  for (int idx = threadIdx.x; idx < CHUNK * D_; idx += 256) {
    int t = idx >> 6, col = idx & 63;
    float bv = bc[bb + idx];
    qe[t][col]  = q[(nb + t) * QD + h * D_ + col] * expf(bv) * SCALE;
    ke[t][col]  = fmaxf(kv[(nb + t) * KVSTR + j * D_ + col], 0.f) * expf(-bv);
    vsh[t][col] = kv[(nb + t) * KVSTR + 256 + j * D_ + col];
    Ss[t][col]  = Sb[sbase + idx];
  }
  __syncthreads();
  {
    int t = threadIdx.x >> 2, s0 = (threadIdx.x & 3) * 16;
#pragma unroll
    for (int l = 0; l < 16; ++l) {
      int s = s0 + l;
      float a = 0.f;
      if (s <= t) {
        for (int i2 = 0; i2 < D_; ++i2) a += qe[t][i2] * ke[s][i2];
      }
      Ash[t][s] = a;
    }
  }
  __syncthreads();
  {
    int t = threadIdx.x >> 2, jv0 = (threadIdx.x & 3) * 16;
    float o[16];
#pragma unroll
    for (int l = 0; l < 16; ++l) o[l] = 0.f;
    for (int i2 = 0; i2 < D_; ++i2) {
      float qv = qe[t][i2];
#pragma unroll
      for (int l = 0; l < 16; ++l) o[l] += qv * Ss[i2][jv0 + l];
    }
    for (int s = 0; s < CHUNK; ++s) {
      float av = Ash[t][s];
#pragma unroll
      for (int l = 0; l < 16; ++l) o[l] += av * vsh[s][jv0 + l];
    }
    size_t obase = (nb + t) * QD + h * D_ + jv0;
#pragma unroll
    for (int l = 0; l < 16; ++l) ob[obase + l] = o[l];
  }
}

// ------------- per-head RMSNorm over D=64; writes bf16 for Wo GEMM ---------
__global__ __launch_bounds__(256) void rms_kernel(const float* __restrict__ ob,
                                                  const float* __restrict__ gw,
                                                  ushort* __restrict__ obh) {
  int row = blockIdx.x * 4 + (threadIdx.x >> 6);
  int lane = threadIdx.x & 63;
  size_t base = (size_t)row * D_;
  float x = ob[base + lane];
  float ss = x * x;
#pragma unroll
  for (int off = 32; off >= 1; off >>= 1) ss += __shfl_xor(ss, off, 64);
  float inv = rsqrtf(ss * (1.0f / D_) + EPS_);
  obh[base + lane] = f2b(gw[lane] * x * inv);
}

extern "C" void kernel_launch(void* const* d_in, const int* in_sizes, int n_in,
                              void* d_out, int out_size, void* d_ws, size_t ws_size,
                              hipStream_t stream) {
  const float* h   = (const float*)d_in[0];
  const float* Wq  = (const float*)d_in[1];
  const float* Wk  = (const float*)d_in[2];
  const float* Wv  = (const float*)d_in[3];
  const float* Wo  = (const float*)d_in[4];
  const float* Wg1 = (const float*)d_in[5];
  const float* Wg2 = (const float*)d_in[6];
  const float* bg2 = (const float*)d_in[7];
  const float* gw  = (const float*)d_in[8];
  float* out = (float*)d_out;

  float* q   = (float*)d_ws;                          // [4096,1024] (reused as ob)
  float* kv  = q  + (size_t)NTOK * QD;                // [4096,512]
  float* g   = kv + (size_t)NTOK * KVSTR;             // [4096,256]
  float* bc  = g  + (size_t)NTOK * KVD;               // [8,2048,64]
  float* Sb  = bc + (size_t)B_ * HKV_ * T_ * D_;      // [8,32,64,64]
  float* Mm  = Sb + (size_t)B_ * HKV_ * NC * D_ * D_; // [8,32,64,64]
  float* E   = Mm + (size_t)B_ * HKV_ * NC * D_ * D_; // [8,32,64]
  ushort* hb   = (ushort*)(E + (size_t)B_ * HKV_ * NC * D_); // [4096,1024] bf16 (reused as obh)
  ushort* Wqt  = hb   + (size_t)NTOK * HID_;          // [1024,1024]
  ushort* Wkvt = Wqt  + (size_t)HID_ * QD;            // [512,1024]
  ushort* Wot  = Wkvt + (size_t)KVSTR * HID_;         // [1024,1024]
  ushort* Wg1t = Wot  + (size_t)HID_ * QD;            // [16,1024]
  float* ob = q;
  ushort* obh = hb;

  dim3 blk(256);
  // bf16 staging: cast h, transpose+cast weights
  cast_bf16_kernel<<<(NTOK * HID_ / 4 + 255) / 256, blk, 0, stream>>>(h, hb, NTOK * HID_ / 4);
  transpose_cast<<<dim3(QD / 64, HID_ / 64), blk, 0, stream>>>(Wq, Wqt, HID_, QD);
  transpose_cast<<<dim3(KVD / 64, HID_ / 64), blk, 0, stream>>>(Wk, Wkvt, HID_, KVD);
  transpose_cast<<<dim3(KVD / 64, HID_ / 64), blk, 0, stream>>>(Wv, Wkvt + (size_t)KVD * HID_, HID_, KVD);
  transpose_cast<<<dim3(HID_ / 64, QD / 64), blk, 0, stream>>>(Wo, Wot, QD, HID_);
  cast_wg1<<<64, blk, 0, stream>>>(Wg1, Wg1t);
  // projections (MFMA); k-relu deferred to consumers, v linear
  gemm_bf16_mfma<true ><<<dim3(QD / 128, NTOK / 128), blk, 0, stream>>>(hb, Wqt, q, NTOK, QD, HID_);
  gemm_bf16_mfma<false><<<dim3(KVSTR / 128, NTOK / 128), blk, 0, stream>>>(hb, Wkvt, kv, NTOK, KVSTR, HID_);
  // fused gate (MFMA stage1 + VALU stage2) + decay cumsum
  gate_fused<<<NTOK / 16, blk, 0, stream>>>(hb, Wg1t, Wg2, bg2, g);
  cumsum_kernel<<<B_ * HKV_ * NC, dim3(64), 0, stream>>>(g, bc);
  // chunked GLA
  chunk_kv<<<B_ * HKV_ * NC, blk, 0, stream>>>(kv, bc, Mm, E);
  state_scan<<<B_ * HKV_ * 16, blk, 0, stream>>>(Mm, E, Sb);
  gla_out<<<B_ * H_ * NC, blk, 0, stream>>>(q, kv, bc, Sb, ob);
  // RMSNorm (bf16 out) + output projection (MFMA)
  rms_kernel<<<NTOK * H_ / 4, blk, 0, stream>>>(ob, gw, obh);
  gemm_bf16_mfma<false><<<dim3(HID_ / 128, NTOK / 128), blk, 0, stream>>>(obh, Wot, out, NTOK, HID_, HID_);
}

// Round 10
// 241.487 us; speedup vs baseline: 6.2275x; 1.3882x over previous
//
#include <hip/hip_runtime.h>
#include <hip/hip_bf16.h>
#include <math.h>

#define B_    2
#define T_    2048
#define HID_  1024
#define H_    16
#define HKV_  4
#define D_    64
#define GLR_  16
#define NTOK  (B_*T_)        // 4096
#define KVD   (HKV_*D_)      // 256
#define KVSTR 512            // fused kv row stride (k:0..255, v:256..511)
#define QD    (H_*D_)        // 1024
#define CHUNK 64
#define NC    (T_/CHUNK)     // 32
#define SCALE 0.125f         // D^-0.5
#define EPS_  1e-6f

typedef __attribute__((ext_vector_type(8))) short short8;
typedef __attribute__((ext_vector_type(4))) float f32x4;

__device__ __forceinline__ ushort f2b(float f) {
  __hip_bfloat16 h = __float2bfloat16(f);
  return *reinterpret_cast<ushort*>(&h);
}

// ---------------- f32 -> bf16 cast (vectorized) ----------------
__global__ __launch_bounds__(256) void cast_bf16_kernel(const float* __restrict__ in,
                                                        ushort* __restrict__ out, int n4) {
  int i = blockIdx.x * 256 + threadIdx.x;
  if (i >= n4) return;
  float4 v = *(const float4*)(in + (size_t)i * 4);
  ushort4 o;
  o.x = f2b(v.x); o.y = f2b(v.y); o.z = f2b(v.z); o.w = f2b(v.w);
  *(ushort4*)(out + (size_t)i * 4) = o;
}

// ------------- W[K][N] f32 -> Wt[N][K] bf16 (64x64 LDS tile) -------------
__global__ __launch_bounds__(256) void transpose_cast(const float* __restrict__ W,
                                                      ushort* __restrict__ Wt,
                                                      int K, int N) {
  __shared__ ushort tile[64][65];
  int n0 = blockIdx.x * 64, k0 = blockIdx.y * 64;
  for (int idx = threadIdx.x; idx < 64 * 64; idx += 256) {
    int r = idx >> 6, c = idx & 63;                  // r: k-offset, c: n-offset
    tile[c][r] = f2b(W[(size_t)(k0 + r) * N + n0 + c]);
  }
  __syncthreads();
  for (int idx = threadIdx.x; idx < 64 * 64; idx += 256) {
    int r = idx >> 6, c = idx & 63;                  // r: n-offset, c: k-offset
    Wt[(size_t)(n0 + r) * K + k0 + c] = tile[r][c];
  }
}

// ------------- Wg1[1024,16] f32 -> Wg1t[16][1024] bf16 -------------
__global__ __launch_bounds__(256) void cast_wg1(const float* __restrict__ Wg1,
                                                ushort* __restrict__ Wg1t) {
  int idx = blockIdx.x * 256 + threadIdx.x;   // 0..16383
  int kk = idx >> 4, n = idx & 15;
  Wg1t[(size_t)n * HID_ + kk] = f2b(Wg1[(size_t)kk * GLR_ + n]);
}

// -------- bf16 MFMA GEMM: C[M,N] = act(A[M,K] @ Bt[N,K]^T), f32 out --------
// 128x128 tile, BK=32, 4 waves (2x2), each wave 64x64 via 4x4 16x16x32 frags.
template<bool RELU>
__global__ __launch_bounds__(256) void gemm_bf16_mfma(const ushort* __restrict__ A,
                                                      const ushort* __restrict__ Bt,
                                                      float* __restrict__ C,
                                                      int M, int N, int K) {
  __shared__ ushort As[128][40];   // +8 pad: row stride 80B = 5x16B (aligned, spread banks)
  __shared__ ushort Bs[128][40];
  const int t = threadIdx.x;
  const int rowBase = blockIdx.y * 128, colBase = blockIdx.x * 128;
  const int lane = t & 63, w = t >> 6;
  const int wr = w >> 1, wc = w & 1;
  const int lrow = lane & 15, hi = lane >> 4;
  f32x4 acc[4][4];
#pragma unroll
  for (int mi = 0; mi < 4; ++mi)
#pragma unroll
    for (int ni = 0; ni < 4; ++ni) acc[mi][ni] = (f32x4){0.f, 0.f, 0.f, 0.f};

  for (int k0 = 0; k0 < K; k0 += 32) {
#pragma unroll
    for (int l = 0; l < 2; ++l) {
      int idx = t + (l << 8);                 // 0..511
      int row = idx >> 2, ch = (idx & 3) << 3;
      *(short8*)&As[row][ch] = *(const short8*)&A[(size_t)(rowBase + row) * K + k0 + ch];
      *(short8*)&Bs[row][ch] = *(const short8*)&Bt[(size_t)(colBase + row) * K + k0 + ch];
    }
    __syncthreads();
    short8 af[4], bf[4];
#pragma unroll
    for (int mi = 0; mi < 4; ++mi)
      af[mi] = *(const short8*)&As[wr * 64 + mi * 16 + lrow][hi * 8];
#pragma unroll
    for (int ni = 0; ni < 4; ++ni)
      bf[ni] = *(const short8*)&Bs[wc * 64 + ni * 16 + lrow][hi * 8];
#pragma unroll
    for (int mi = 0; mi < 4; ++mi)
#pragma unroll
      for (int ni = 0; ni < 4; ++ni)
        acc[mi][ni] = __builtin_amdgcn_mfma_f32_16x16x32_bf16(af[mi], bf[ni], acc[mi][ni], 0, 0, 0);
    __syncthreads();
  }
#pragma unroll
  for (int mi = 0; mi < 4; ++mi)
#pragma unroll
    for (int ni = 0; ni < 4; ++ni)
#pragma unroll
      for (int r = 0; r < 4; ++r) {
        int gm = rowBase + wr * 64 + mi * 16 + hi * 4 + r;
        int gn = colBase + wc * 64 + ni * 16 + lrow;
        float val = acc[mi][ni][r];
        if (RELU) val = fmaxf(val, 0.f);
        C[(size_t)gm * N + gn] = val;
      }
}

// ------ fused gate: gt = h@Wg1 (MFMA, K-split), g = logsig(gt@Wg2+bg2)/16 ---
// 256 blocks x 256 threads; block handles 16 tokens.
__global__ __launch_bounds__(256) void gate_fused(const ushort* __restrict__ hb,
                                                  const ushort* __restrict__ Wg1t,
                                                  const float* __restrict__ Wg2,
                                                  const float* __restrict__ bg2,
                                                  float* __restrict__ g) {
  __shared__ float part[4][16][17];
  __shared__ float gts[16][17];
  const int t = threadIdx.x, lane = t & 63, w = t >> 6;
  const int lrow = lane & 15, hi = lane >> 4;
  const int nb0 = blockIdx.x * 16;
  // stage 1: gt[16 tok][16 n] via MFMA, wave w covers K slice [w*256,(w+1)*256)
  f32x4 acc = (f32x4){0.f, 0.f, 0.f, 0.f};
  const int kb = w * 256;
#pragma unroll
  for (int kk = 0; kk < 8; ++kk) {
    int k0 = kb + kk * 32 + hi * 8;
    short8 a = *(const short8*)&hb[(size_t)(nb0 + lrow) * HID_ + k0];
    short8 b = *(const short8*)&Wg1t[(size_t)lrow * HID_ + k0];
    acc = __builtin_amdgcn_mfma_f32_16x16x32_bf16(a, b, acc, 0, 0, 0);
  }
#pragma unroll
  for (int r = 0; r < 4; ++r) part[w][hi * 4 + r][lrow] = acc[r];  // [tok][n]
  __syncthreads();
  {
    int tok = t >> 4, n = t & 15;
    gts[tok][n] = part[0][tok][n] + part[1][tok][n] + part[2][tok][n] + part[3][tok][n];
  }
  __syncthreads();
  // stage 2: thread = column c; 16 tokens
  const int c = t;
  const float bias = bg2[c];
#pragma unroll 4
  for (int tok = 0; tok < 16; ++tok) {
    float acc2 = bias;
#pragma unroll
    for (int r = 0; r < GLR_; ++r) acc2 += gts[tok][r] * Wg2[r * KVD + c];
    float ls = fminf(acc2, 0.f) - log1pf(expf(-fabsf(acc2)));
    g[(size_t)(nb0 + tok) * KVD + c] = ls * (1.0f / 16.0f);
  }
}

// ------------- per-chunk inclusive cumsum of log-decay over t --------------
__global__ void cumsum_kernel(const float* __restrict__ g, float* __restrict__ bc) {
  int blk = blockIdx.x;             // (b*HKV+j)*NC + c
  int c = blk % NC, gj = blk / NC;
  int b = gj / HKV_, j = gj % HKV_;
  int d = threadIdx.x;
  size_t gbase = ((size_t)(b * T_ + c * CHUNK)) * KVD + j * D_ + d;
  size_t obase = ((size_t)gj * T_ + c * CHUNK) * D_ + d;
  float run = 0.f;
  for (int t = 0; t < CHUNK; ++t) {
    run += g[gbase + (size_t)t * KVD];
    bc[obase + (size_t)t * D_] = run;
  }
}

// ---- per-chunk decayed K^T V, TRANSPOSED out: Mt[jv][i]; relu(k) here ----
__global__ __launch_bounds__(256) void chunk_kv(const float* __restrict__ kv,
                                                const float* __restrict__ bc,
                                                float* __restrict__ Mt,
                                                float* __restrict__ E) {
  __shared__ float ks[CHUNK][D_ + 1];
  __shared__ float vs[CHUNK][D_ + 1];
  __shared__ float blast[D_];
  int blk = blockIdx.x;             // gj*NC + c
  int c = blk % NC, gj = blk / NC;
  int b = gj >> 2, j = gj & 3;
  size_t kb = ((size_t)(b * T_ + c * CHUNK)) * KVSTR + j * D_;
  size_t bb = ((size_t)gj * T_ + c * CHUNK) * D_;
  if (threadIdx.x < D_) blast[threadIdx.x] = bc[bb + (size_t)(CHUNK - 1) * D_ + threadIdx.x];
  __syncthreads();
  for (int idx = threadIdx.x; idx < CHUNK * D_; idx += 256) {
    int t = idx >> 6, col = idx & 63;
    float bv = bc[bb + idx];
    ks[t][col] = fmaxf(kv[kb + (size_t)t * KVSTR + col], 0.f) * expf(blast[col] - bv);
    vs[t][col] = kv[kb + (size_t)t * KVSTR + 256 + col];
  }
  __syncthreads();
  int jv = threadIdx.x >> 2;            // v-dim row of Mt
  int i0 = (threadIdx.x & 3) * 16;      // k-dim col group
  float acc[16];
#pragma unroll
  for (int l = 0; l < 16; ++l) acc[l] = 0.f;
  for (int t = 0; t < CHUNK; ++t) {
    float vt_ = vs[t][jv];
#pragma unroll
    for (int l = 0; l < 16; ++l) acc[l] += vt_ * ks[t][i0 + l];
  }
  size_t mbase = (size_t)blk * D_ * D_ + (size_t)jv * D_ + i0;
#pragma unroll
  for (int l = 0; l < 16; ++l) Mt[mbase + l] = acc[l];
  if (threadIdx.x < D_) E[(size_t)blk * D_ + threadIdx.x] = expf(blast[threadIdx.x]);
}

// ---- elementwise inter-chunk scan on TRANSPOSED state: Sbt[gj][c][jv][i] ----
__global__ __launch_bounds__(256) void state_scan(const float* __restrict__ Mt,
                                                  const float* __restrict__ E,
                                                  float* __restrict__ Sbt) {
  int gj = blockIdx.x >> 4;
  int elem = ((blockIdx.x & 15) << 8) + threadIdx.x;   // jv*64 + i
  int i = elem & 63;                                   // k-dim index
  float S = 0.f;
#pragma unroll
  for (int c = 0; c < NC; ++c) {
    size_t base = ((size_t)gj * NC + c) * (D_ * D_) + elem;
    Sbt[base] = S;
    S = E[((size_t)gj * NC + c) * D_ + i] * S + Mt[base];
  }
}

// ------------- per-chunk output via MFMA (1024 blocks); relu(k) here -------
// A = causal(qe @ ke^T); O = qe @ S + A @ v. All operands bf16 in LDS.
__global__ __launch_bounds__(256) void gla_out(const float* __restrict__ q,
                                               const float* __restrict__ kv,
                                               const float* __restrict__ bc,
                                               const float* __restrict__ Sbt,
                                               float* __restrict__ ob) {
  __shared__ ushort qes[64][72];   // qe[t][d]  (stride 144B = 9x16B, 2-way free)
  __shared__ ushort kes[64][72];   // ke[s][d]
  __shared__ ushort vts[64][72];   // v^T[jv][s]
  __shared__ ushort sts[64][72];   // S^T[jv][d]
  __shared__ ushort Al [64][72];   // A[t][s] causal-masked, bf16
  int blk = blockIdx.x;                 // (b*H + h)*NC + c
  int c = blk % NC, bh = blk / NC;
  int b = bh / H_, h = bh % H_;
  int j = h >> 2, gj = b * HKV_ + j;
  size_t nb = (size_t)(b * T_ + c * CHUNK);
  size_t bb = ((size_t)gj * T_ + c * CHUNK) * D_;
  size_t sbase = ((size_t)gj * NC + c) * D_ * D_;
  const int t = threadIdx.x, lane = t & 63, w = t >> 6;
  const int lrow = lane & 15, hi = lane >> 4;
  for (int idx = t; idx < CHUNK * D_; idx += 256) {
    int tt = idx >> 6, col = idx & 63;
    float bv = bc[bb + idx];
    qes[tt][col] = f2b(q[(nb + tt) * QD + h * D_ + col] * expf(bv) * SCALE);
    kes[tt][col] = f2b(fmaxf(kv[(nb + tt) * KVSTR + j * D_ + col], 0.f) * expf(-bv));
    vts[col][tt] = f2b(kv[(nb + tt) * KVSTR + 256 + j * D_ + col]);
    sts[tt][col] = f2b(Sbt[sbase + idx]);   // tt=jv, col=i(d)
  }
  __syncthreads();
  // phase A: wave w computes A tile-row ti=w (tiles si<=ti nonzero)
  {
    const int ti = w;
#pragma unroll
    for (int si = 0; si < 4; ++si) {
      f32x4 acc = (f32x4){0.f, 0.f, 0.f, 0.f};
      if (si <= ti) {
#pragma unroll
        for (int kk = 0; kk < 2; ++kk) {
          short8 a  = *(const short8*)&qes[ti * 16 + lrow][kk * 32 + hi * 8];
          short8 bf = *(const short8*)&kes[si * 16 + lrow][kk * 32 + hi * 8];
          acc = __builtin_amdgcn_mfma_f32_16x16x32_bf16(a, bf, acc, 0, 0, 0);
        }
      }
#pragma unroll
      for (int r = 0; r < 4; ++r) {
        int grow = ti * 16 + hi * 4 + r, gcol = si * 16 + lrow;
        Al[grow][gcol] = f2b(gcol <= grow ? acc[r] : 0.f);
      }
    }
  }
  __syncthreads();
  // phase O: wave w computes O rows [w*16, w*16+16): O = qe@S + A@v
  {
#pragma unroll
    for (int ni = 0; ni < 4; ++ni) {
      f32x4 acc = (f32x4){0.f, 0.f, 0.f, 0.f};
#pragma unroll
      for (int kk = 0; kk < 2; ++kk) {
        short8 a  = *(const short8*)&qes[w * 16 + lrow][kk * 32 + hi * 8];
        short8 bf = *(const short8*)&sts[ni * 16 + lrow][kk * 32 + hi * 8];
        acc = __builtin_amdgcn_mfma_f32_16x16x32_bf16(a, bf, acc, 0, 0, 0);
      }
#pragma unroll
      for (int kk = 0; kk < 2; ++kk) {
        short8 a  = *(const short8*)&Al[w * 16 + lrow][kk * 32 + hi * 8];
        short8 bf = *(const short8*)&vts[ni * 16 + lrow][kk * 32 + hi * 8];
        acc = __builtin_amdgcn_mfma_f32_16x16x32_bf16(a, bf, acc, 0, 0, 0);
      }
#pragma unroll
      for (int r = 0; r < 4; ++r)
        ob[(nb + w * 16 + hi * 4 + r) * QD + h * D_ + ni * 16 + lrow] = acc[r];
    }
  }
}

// ------------- per-head RMSNorm over D=64; writes bf16 for Wo GEMM ---------
__global__ __launch_bounds__(256) void rms_kernel(const float* __restrict__ ob,
                                                  const float* __restrict__ gw,
                                                  ushort* __restrict__ obh) {
  int row = blockIdx.x * 4 + (threadIdx.x >> 6);
  int lane = threadIdx.x & 63;
  size_t base = (size_t)row * D_;
  float x = ob[base + lane];
  float ss = x * x;
#pragma unroll
  for (int off = 32; off >= 1; off >>= 1) ss += __shfl_xor(ss, off, 64);
  float inv = rsqrtf(ss * (1.0f / D_) + EPS_);
  obh[base + lane] = f2b(gw[lane] * x * inv);
}

extern "C" void kernel_launch(void* const* d_in, const int* in_sizes, int n_in,
                              void* d_out, int out_size, void* d_ws, size_t ws_size,
                              hipStream_t stream) {
  const float* h   = (const float*)d_in[0];
  const float* Wq  = (const float*)d_in[1];
  const float* Wk  = (const float*)d_in[2];
  const float* Wv  = (const float*)d_in[3];
  const float* Wo  = (const float*)d_in[4];
  const float* Wg1 = (const float*)d_in[5];
  const float* Wg2 = (const float*)d_in[6];
  const float* bg2 = (const float*)d_in[7];
  const float* gw  = (const float*)d_in[8];
  float* out = (float*)d_out;

  float* q   = (float*)d_ws;                          // [4096,1024] (reused as ob)
  float* kv  = q  + (size_t)NTOK * QD;                // [4096,512]
  float* g   = kv + (size_t)NTOK * KVSTR;             // [4096,256]
  float* bc  = g  + (size_t)NTOK * KVD;               // [8,2048,64]
  float* Sbt = bc + (size_t)B_ * HKV_ * T_ * D_;      // [8,32,64,64] transposed state
  float* Mt  = Sbt + (size_t)B_ * HKV_ * NC * D_ * D_;// [8,32,64,64] transposed KtV
  float* E   = Mt + (size_t)B_ * HKV_ * NC * D_ * D_; // [8,32,64]
  ushort* hb   = (ushort*)(E + (size_t)B_ * HKV_ * NC * D_); // [4096,1024] bf16 (reused as obh)
  ushort* Wqt  = hb   + (size_t)NTOK * HID_;          // [1024,1024]
  ushort* Wkvt = Wqt  + (size_t)HID_ * QD;            // [512,1024]
  ushort* Wot  = Wkvt + (size_t)KVSTR * HID_;         // [1024,1024]
  ushort* Wg1t = Wot  + (size_t)HID_ * QD;            // [16,1024]
  float* ob = q;
  ushort* obh = hb;

  dim3 blk(256);
  // bf16 staging: cast h, transpose+cast weights
  cast_bf16_kernel<<<(NTOK * HID_ / 4 + 255) / 256, blk, 0, stream>>>(h, hb, NTOK * HID_ / 4);
  transpose_cast<<<dim3(QD / 64, HID_ / 64), blk, 0, stream>>>(Wq, Wqt, HID_, QD);
  transpose_cast<<<dim3(KVD / 64, HID_ / 64), blk, 0, stream>>>(Wk, Wkvt, HID_, KVD);
  transpose_cast<<<dim3(KVD / 64, HID_ / 64), blk, 0, stream>>>(Wv, Wkvt + (size_t)KVD * HID_, HID_, KVD);
  transpose_cast<<<dim3(HID_ / 64, QD / 64), blk, 0, stream>>>(Wo, Wot, QD, HID_);
  cast_wg1<<<64, blk, 0, stream>>>(Wg1, Wg1t);
  // projections (MFMA); k-relu deferred to consumers, v linear
  gemm_bf16_mfma<true ><<<dim3(QD / 128, NTOK / 128), blk, 0, stream>>>(hb, Wqt, q, NTOK, QD, HID_);
  gemm_bf16_mfma<false><<<dim3(KVSTR / 128, NTOK / 128), blk, 0, stream>>>(hb, Wkvt, kv, NTOK, KVSTR, HID_);
  // fused gate (MFMA stage1 + VALU stage2) + decay cumsum
  gate_fused<<<NTOK / 16, blk, 0, stream>>>(hb, Wg1t, Wg2, bg2, g);
  cumsum_kernel<<<B_ * HKV_ * NC, dim3(64), 0, stream>>>(g, bc);
  // chunked GLA (transposed M/S for MFMA b-fragments)
  chunk_kv<<<B_ * HKV_ * NC, blk, 0, stream>>>(kv, bc, Mt, E);
  state_scan<<<B_ * HKV_ * 16, blk, 0, stream>>>(Mt, E, Sbt);
  gla_out<<<B_ * H_ * NC, blk, 0, stream>>>(q, kv, bc, Sbt, ob);
  // RMSNorm (bf16 out) + output projection (MFMA)
  rms_kernel<<<NTOK * H_ / 4, blk, 0, stream>>>(ob, gw, obh);
  gemm_bf16_mfma<false><<<dim3(HID_ / 128, NTOK / 128), blk, 0, stream>>>(obh, Wot, out, NTOK, HID_, HID_);
}

// Round 11
// 228.051 us; speedup vs baseline: 6.5944x; 1.0589x over previous
//
#include <hip/hip_runtime.h>
#include <hip/hip_bf16.h>
#include <math.h>

#define B_    2
#define T_    2048
#define HID_  1024
#define H_    16
#define HKV_  4
#define D_    64
#define GLR_  16
#define NTOK  (B_*T_)        // 4096
#define KVD   (HKV_*D_)      // 256
#define KVSTR 512            // fused kv row stride (k:0..255, v:256..511)
#define QD    (H_*D_)        // 1024
#define NPROJ (QD+KVSTR)     // 1536 fused projection width
#define CHUNK 64
#define NC    (T_/CHUNK)     // 32
#define SCALE 0.125f         // D^-0.5
#define EPS_  1e-6f

typedef __attribute__((ext_vector_type(8))) short short8;
typedef __attribute__((ext_vector_type(4))) float f32x4;

__device__ __forceinline__ ushort f2b(float f) {
  __hip_bfloat16 h = __float2bfloat16(f);
  return *reinterpret_cast<ushort*>(&h);
}

// ---------------- f32 -> bf16 cast (vectorized) ----------------
__global__ __launch_bounds__(256) void cast_bf16_kernel(const float* __restrict__ in,
                                                        ushort* __restrict__ out, int n4) {
  int i = blockIdx.x * 256 + threadIdx.x;
  if (i >= n4) return;
  float4 v = *(const float4*)(in + (size_t)i * 4);
  ushort4 o;
  o.x = f2b(v.x); o.y = f2b(v.y); o.z = f2b(v.z); o.w = f2b(v.w);
  *(ushort4*)(out + (size_t)i * 4) = o;
}

// ------------- W[K][N] f32 -> Wt[N][K] bf16 (64x64 LDS tile) -------------
__global__ __launch_bounds__(256) void transpose_cast(const float* __restrict__ W,
                                                      ushort* __restrict__ Wt,
                                                      int K, int N) {
  __shared__ ushort tile[64][65];
  int n0 = blockIdx.x * 64, k0 = blockIdx.y * 64;
  for (int idx = threadIdx.x; idx < 64 * 64; idx += 256) {
    int r = idx >> 6, c = idx & 63;                  // r: k-offset, c: n-offset
    tile[c][r] = f2b(W[(size_t)(k0 + r) * N + n0 + c]);
  }
  __syncthreads();
  for (int idx = threadIdx.x; idx < 64 * 64; idx += 256) {
    int r = idx >> 6, c = idx & 63;                  // r: n-offset, c: k-offset
    Wt[(size_t)(n0 + r) * K + k0 + c] = tile[r][c];
  }
}

// ------------- Wg1[1024,16] f32 -> Wg1t[16][1024] bf16 -------------
__global__ __launch_bounds__(256) void cast_wg1(const float* __restrict__ Wg1,
                                                ushort* __restrict__ Wg1t) {
  int idx = blockIdx.x * 256 + threadIdx.x;   // 0..16383
  int kk = idx >> 4, n = idx & 15;
  Wg1t[(size_t)n * HID_ + kk] = f2b(Wg1[(size_t)kk * GLR_ + n]);
}

// ---- fused projection GEMM: [q | kv] = hb @ [Wqt;Wkvt]^T, relu on q cols ---
// 128x128 tile, BK=32, 4 waves (2x2); N = 1536.
__global__ __launch_bounds__(256) void gemm_proj(const ushort* __restrict__ A,
                                                 const ushort* __restrict__ Bt,
                                                 float* __restrict__ q,
                                                 float* __restrict__ kvo) {
  __shared__ ushort As[128][40];   // +8 pad: row stride 80B (2-way bank alias, free)
  __shared__ ushort Bs[128][40];
  const int t = threadIdx.x;
  const int rowBase = blockIdx.y * 128, colBase = blockIdx.x * 128;
  const int lane = t & 63, w = t >> 6;
  const int wr = w >> 1, wc = w & 1;
  const int lrow = lane & 15, hi = lane >> 4;
  const int K = HID_;
  f32x4 acc[4][4];
#pragma unroll
  for (int mi = 0; mi < 4; ++mi)
#pragma unroll
    for (int ni = 0; ni < 4; ++ni) acc[mi][ni] = (f32x4){0.f, 0.f, 0.f, 0.f};

  for (int k0 = 0; k0 < K; k0 += 32) {
#pragma unroll
    for (int l = 0; l < 2; ++l) {
      int idx = t + (l << 8);
      int row = idx >> 2, ch = (idx & 3) << 3;
      *(short8*)&As[row][ch] = *(const short8*)&A[(size_t)(rowBase + row) * K + k0 + ch];
      *(short8*)&Bs[row][ch] = *(const short8*)&Bt[(size_t)(colBase + row) * K + k0 + ch];
    }
    __syncthreads();
    short8 af[4], bf[4];
#pragma unroll
    for (int mi = 0; mi < 4; ++mi)
      af[mi] = *(const short8*)&As[wr * 64 + mi * 16 + lrow][hi * 8];
#pragma unroll
    for (int ni = 0; ni < 4; ++ni)
      bf[ni] = *(const short8*)&Bs[wc * 64 + ni * 16 + lrow][hi * 8];
#pragma unroll
    for (int mi = 0; mi < 4; ++mi)
#pragma unroll
      for (int ni = 0; ni < 4; ++ni)
        acc[mi][ni] = __builtin_amdgcn_mfma_f32_16x16x32_bf16(af[mi], bf[ni], acc[mi][ni], 0, 0, 0);
    __syncthreads();
  }
#pragma unroll
  for (int mi = 0; mi < 4; ++mi)
#pragma unroll
    for (int ni = 0; ni < 4; ++ni)
#pragma unroll
      for (int r = 0; r < 4; ++r) {
        int gm = rowBase + wr * 64 + mi * 16 + hi * 4 + r;
        int gn = colBase + wc * 64 + ni * 16 + lrow;
        float val = acc[mi][ni][r];
        if (gn < QD) q[(size_t)gm * QD + gn] = fmaxf(val, 0.f);
        else         kvo[(size_t)gm * KVSTR + gn - QD] = val;
      }
}

// -------- bf16 MFMA GEMM (Wo): C[M,N] = A[M,K] @ Bt[N,K]^T, f32 out --------
__global__ __launch_bounds__(256) void gemm_bf16_mfma(const ushort* __restrict__ A,
                                                      const ushort* __restrict__ Bt,
                                                      float* __restrict__ C,
                                                      int M, int N, int K) {
  __shared__ ushort As[128][40];
  __shared__ ushort Bs[128][40];
  const int t = threadIdx.x;
  const int rowBase = blockIdx.y * 128, colBase = blockIdx.x * 128;
  const int lane = t & 63, w = t >> 6;
  const int wr = w >> 1, wc = w & 1;
  const int lrow = lane & 15, hi = lane >> 4;
  f32x4 acc[4][4];
#pragma unroll
  for (int mi = 0; mi < 4; ++mi)
#pragma unroll
    for (int ni = 0; ni < 4; ++ni) acc[mi][ni] = (f32x4){0.f, 0.f, 0.f, 0.f};

  for (int k0 = 0; k0 < K; k0 += 32) {
#pragma unroll
    for (int l = 0; l < 2; ++l) {
      int idx = t + (l << 8);
      int row = idx >> 2, ch = (idx & 3) << 3;
      *(short8*)&As[row][ch] = *(const short8*)&A[(size_t)(rowBase + row) * K + k0 + ch];
      *(short8*)&Bs[row][ch] = *(const short8*)&Bt[(size_t)(colBase + row) * K + k0 + ch];
    }
    __syncthreads();
    short8 af[4], bf[4];
#pragma unroll
    for (int mi = 0; mi < 4; ++mi)
      af[mi] = *(const short8*)&As[wr * 64 + mi * 16 + lrow][hi * 8];
#pragma unroll
    for (int ni = 0; ni < 4; ++ni)
      bf[ni] = *(const short8*)&Bs[wc * 64 + ni * 16 + lrow][hi * 8];
#pragma unroll
    for (int mi = 0; mi < 4; ++mi)
#pragma unroll
      for (int ni = 0; ni < 4; ++ni)
        acc[mi][ni] = __builtin_amdgcn_mfma_f32_16x16x32_bf16(af[mi], bf[ni], acc[mi][ni], 0, 0, 0);
    __syncthreads();
  }
#pragma unroll
  for (int mi = 0; mi < 4; ++mi)
#pragma unroll
    for (int ni = 0; ni < 4; ++ni)
#pragma unroll
      for (int r = 0; r < 4; ++r) {
        int gm = rowBase + wr * 64 + mi * 16 + hi * 4 + r;
        int gn = colBase + wc * 64 + ni * 16 + lrow;
        C[(size_t)gm * N + gn] = acc[mi][ni][r];
      }
}

// --- fused gate + decay cumsum: one block per 64-token chunk (64 blocks) ---
// stage1: gt[64,16] = hb @ Wg1t^T (each wave: 16 tokens, full K, 32 MFMA)
// stage2: thread=col c; logsigmoid(gt@Wg2+bg2)/16 with running cumsum -> bc
__global__ __launch_bounds__(256) void gate_cumsum(const ushort* __restrict__ hb,
                                                   const ushort* __restrict__ Wg1t,
                                                   const float* __restrict__ Wg2,
                                                   const float* __restrict__ bg2,
                                                   float* __restrict__ bc) {
  __shared__ float gts[CHUNK][GLR_ + 1];
  const int t = threadIdx.x, lane = t & 63, w = t >> 6;
  const int lrow = lane & 15, hi = lane >> 4;
  const int c0 = blockIdx.x * CHUNK;          // global token base
  const int b = c0 / T_, tloc = c0 % T_;
  // stage 1
  {
    f32x4 acc = (f32x4){0.f, 0.f, 0.f, 0.f};
#pragma unroll
    for (int kk = 0; kk < 32; ++kk) {
      int k0 = kk * 32 + hi * 8;
      short8 a = *(const short8*)&hb[(size_t)(c0 + w * 16 + lrow) * HID_ + k0];
      short8 bf = *(const short8*)&Wg1t[(size_t)lrow * HID_ + k0];
      acc = __builtin_amdgcn_mfma_f32_16x16x32_bf16(a, bf, acc, 0, 0, 0);
    }
#pragma unroll
    for (int r = 0; r < 4; ++r) gts[w * 16 + hi * 4 + r][lrow] = acc[r];
  }
  __syncthreads();
  // stage 2
  {
    const int c = t;                          // 0..255
    const int j = c >> 6, d = c & 63;
    const int gj = b * HKV_ + j;
    const float bias = bg2[c];
    float run = 0.f;
    size_t base = ((size_t)gj * T_ + tloc) * D_ + d;
    for (int tok = 0; tok < CHUNK; ++tok) {
      float acc2 = bias;
#pragma unroll
      for (int r = 0; r < GLR_; ++r) acc2 += gts[tok][r] * Wg2[r * KVD + c];
      float ls = fminf(acc2, 0.f) - log1pf(expf(-fabsf(acc2)));
      run += ls * (1.0f / 16.0f);
      bc[base + (size_t)tok * D_] = run;
    }
  }
}

// ---- per-chunk decayed K^T V, TRANSPOSED out: Mt[jv][i]; relu(k) here ----
__global__ __launch_bounds__(256) void chunk_kv(const float* __restrict__ kv,
                                                const float* __restrict__ bc,
                                                float* __restrict__ Mt,
                                                float* __restrict__ E) {
  __shared__ float ks[CHUNK][D_ + 1];
  __shared__ float vs[CHUNK][D_ + 1];
  __shared__ float blast[D_];
  int blk = blockIdx.x;             // gj*NC + c
  int c = blk % NC, gj = blk / NC;
  int b = gj >> 2, j = gj & 3;
  size_t kb = ((size_t)(b * T_ + c * CHUNK)) * KVSTR + j * D_;
  size_t bb = ((size_t)gj * T_ + c * CHUNK) * D_;
  if (threadIdx.x < D_) blast[threadIdx.x] = bc[bb + (size_t)(CHUNK - 1) * D_ + threadIdx.x];
  __syncthreads();
  for (int idx = threadIdx.x; idx < CHUNK * D_; idx += 256) {
    int t = idx >> 6, col = idx & 63;
    float bv = bc[bb + idx];
    ks[t][col] = fmaxf(kv[kb + (size_t)t * KVSTR + col], 0.f) * expf(blast[col] - bv);
    vs[t][col] = kv[kb + (size_t)t * KVSTR + 256 + col];
  }
  __syncthreads();
  int jv = threadIdx.x >> 2;            // v-dim row of Mt
  int i0 = (threadIdx.x & 3) * 16;      // k-dim col group
  float acc[16];
#pragma unroll
  for (int l = 0; l < 16; ++l) acc[l] = 0.f;
  for (int t = 0; t < CHUNK; ++t) {
    float vt_ = vs[t][jv];
#pragma unroll
    for (int l = 0; l < 16; ++l) acc[l] += vt_ * ks[t][i0 + l];
  }
  size_t mbase = (size_t)blk * D_ * D_ + (size_t)jv * D_ + i0;
#pragma unroll
  for (int l = 0; l < 16; ++l) Mt[mbase + l] = acc[l];
  if (threadIdx.x < D_) E[(size_t)blk * D_ + threadIdx.x] = expf(blast[threadIdx.x]);
}

// ---- elementwise inter-chunk scan on TRANSPOSED state: Sbt[gj][c][jv][i] ----
__global__ __launch_bounds__(256) void state_scan(const float* __restrict__ Mt,
                                                  const float* __restrict__ E,
                                                  float* __restrict__ Sbt) {
  int gj = blockIdx.x >> 4;
  int elem = ((blockIdx.x & 15) << 8) + threadIdx.x;   // jv*64 + i
  int i = elem & 63;                                   // k-dim index
  float S = 0.f;
#pragma unroll
  for (int c = 0; c < NC; ++c) {
    size_t base = ((size_t)gj * NC + c) * (D_ * D_) + elem;
    Sbt[base] = S;
    S = E[((size_t)gj * NC + c) * D_ + i] * S + Mt[base];
  }
}

// ---- per-chunk output via MFMA + fused RMSNorm (1024 blocks); bf16 out ----
// A = causal(qe @ ke^T); O = qe @ S + A @ v; obh = gw * O * rsqrt(mean(O^2))
__global__ __launch_bounds__(256) void gla_out(const float* __restrict__ q,
                                               const float* __restrict__ kv,
                                               const float* __restrict__ bc,
                                               const float* __restrict__ Sbt,
                                               const float* __restrict__ gw,
                                               ushort* __restrict__ obh) {
  __shared__ ushort qes[64][72];   // qe[t][d]  (stride 144B, 2-way free)
  __shared__ ushort kes[64][72];   // ke[s][d]
  __shared__ ushort vts[64][72];   // v^T[jv][s]
  __shared__ ushort sts[64][72];   // S^T[jv][d]
  __shared__ ushort Al [64][72];   // A[t][s] causal-masked, bf16
  int blk = blockIdx.x;                 // (b*H + h)*NC + c
  int c = blk % NC, bh = blk / NC;
  int b = bh / H_, h = bh % H_;
  int j = h >> 2, gj = b * HKV_ + j;
  size_t nb = (size_t)(b * T_ + c * CHUNK);
  size_t bb = ((size_t)gj * T_ + c * CHUNK) * D_;
  size_t sbase = ((size_t)gj * NC + c) * D_ * D_;
  const int t = threadIdx.x, lane = t & 63, w = t >> 6;
  const int lrow = lane & 15, hi = lane >> 4;
  for (int idx = t; idx < CHUNK * D_; idx += 256) {
    int tt = idx >> 6, col = idx & 63;
    float bv = bc[bb + idx];
    qes[tt][col] = f2b(q[(nb + tt) * QD + h * D_ + col] * expf(bv) * SCALE);
    kes[tt][col] = f2b(fmaxf(kv[(nb + tt) * KVSTR + j * D_ + col], 0.f) * expf(-bv));
    vts[col][tt] = f2b(kv[(nb + tt) * KVSTR + 256 + j * D_ + col]);
    sts[tt][col] = f2b(Sbt[sbase + idx]);   // tt=jv, col=i(d)
  }
  __syncthreads();
  // phase A: wave w computes A tile-row ti=w (tiles si<=ti nonzero)
  {
    const int ti = w;
#pragma unroll
    for (int si = 0; si < 4; ++si) {
      f32x4 acc = (f32x4){0.f, 0.f, 0.f, 0.f};
      if (si <= ti) {
#pragma unroll
        for (int kk = 0; kk < 2; ++kk) {
          short8 a  = *(const short8*)&qes[ti * 16 + lrow][kk * 32 + hi * 8];
          short8 bf = *(const short8*)&kes[si * 16 + lrow][kk * 32 + hi * 8];
          acc = __builtin_amdgcn_mfma_f32_16x16x32_bf16(a, bf, acc, 0, 0, 0);
        }
      }
#pragma unroll
      for (int r = 0; r < 4; ++r) {
        int grow = ti * 16 + hi * 4 + r, gcol = si * 16 + lrow;
        Al[grow][gcol] = f2b(gcol <= grow ? acc[r] : 0.f);
      }
    }
  }
  __syncthreads();
  // phase O: O = qe@S + A@v, kept in regs; then per-row RMSNorm, bf16 store
  {
    float o[4][4];                       // [ni][r]
#pragma unroll
    for (int ni = 0; ni < 4; ++ni) {
      f32x4 acc = (f32x4){0.f, 0.f, 0.f, 0.f};
#pragma unroll
      for (int kk = 0; kk < 2; ++kk) {
        short8 a  = *(const short8*)&qes[w * 16 + lrow][kk * 32 + hi * 8];
        short8 bf = *(const short8*)&sts[ni * 16 + lrow][kk * 32 + hi * 8];
        acc = __builtin_amdgcn_mfma_f32_16x16x32_bf16(a, bf, acc, 0, 0, 0);
      }
#pragma unroll
      for (int kk = 0; kk < 2; ++kk) {
        short8 a  = *(const short8*)&Al[w * 16 + lrow][kk * 32 + hi * 8];
        short8 bf = *(const short8*)&vts[ni * 16 + lrow][kk * 32 + hi * 8];
        acc = __builtin_amdgcn_mfma_f32_16x16x32_bf16(a, bf, acc, 0, 0, 0);
      }
#pragma unroll
      for (int r = 0; r < 4; ++r) o[ni][r] = acc[r];
    }
#pragma unroll
    for (int r = 0; r < 4; ++r) {
      float ss = o[0][r] * o[0][r] + o[1][r] * o[1][r]
               + o[2][r] * o[2][r] + o[3][r] * o[3][r];
      ss += __shfl_xor(ss, 1, 64);       // reduce across the 16 lrow lanes
      ss += __shfl_xor(ss, 2, 64);       // (masks <16 stay within hi-group)
      ss += __shfl_xor(ss, 4, 64);
      ss += __shfl_xor(ss, 8, 64);
      float inv = rsqrtf(ss * (1.0f / D_) + EPS_);
      size_t rowoff = (nb + w * 16 + hi * 4 + r) * QD + h * D_;
#pragma unroll
      for (int ni = 0; ni < 4; ++ni) {
        int d = ni * 16 + lrow;
        obh[rowoff + d] = f2b(gw[d] * o[ni][r] * inv);
      }
    }
  }
}

extern "C" void kernel_launch(void* const* d_in, const int* in_sizes, int n_in,
                              void* d_out, int out_size, void* d_ws, size_t ws_size,
                              hipStream_t stream) {
  const float* h   = (const float*)d_in[0];
  const float* Wq  = (const float*)d_in[1];
  const float* Wk  = (const float*)d_in[2];
  const float* Wv  = (const float*)d_in[3];
  const float* Wo  = (const float*)d_in[4];
  const float* Wg1 = (const float*)d_in[5];
  const float* Wg2 = (const float*)d_in[6];
  const float* bg2 = (const float*)d_in[7];
  const float* gw  = (const float*)d_in[8];
  float* out = (float*)d_out;

  float* q   = (float*)d_ws;                          // [4096,1024]
  float* kv  = q  + (size_t)NTOK * QD;                // [4096,512]
  float* bc  = kv + (size_t)NTOK * KVSTR;             // [8,2048,64]
  float* Sbt = bc + (size_t)B_ * HKV_ * T_ * D_;      // [8,32,64,64]
  float* Mt  = Sbt + (size_t)B_ * HKV_ * NC * D_ * D_;// [8,32,64,64]
  float* E   = Mt + (size_t)B_ * HKV_ * NC * D_ * D_; // [8,32,64]
  ushort* hb   = (ushort*)(E + (size_t)B_ * HKV_ * NC * D_); // [4096,1024] bf16 (reused as obh)
  ushort* Wqt  = hb   + (size_t)NTOK * HID_;          // [1024,1024] } contiguous ->
  ushort* Wkvt = Wqt  + (size_t)HID_ * QD;            // [512,1024]  } Bt with N=1536
  ushort* Wot  = Wkvt + (size_t)KVSTR * HID_;         // [1024,1024]
  ushort* Wg1t = Wot  + (size_t)HID_ * QD;            // [16,1024]
  ushort* obh = hb;

  dim3 blk(256);
  // bf16 staging: cast h, transpose+cast weights
  cast_bf16_kernel<<<(NTOK * HID_ / 4 + 255) / 256, blk, 0, stream>>>(h, hb, NTOK * HID_ / 4);
  transpose_cast<<<dim3(QD / 64, HID_ / 64), blk, 0, stream>>>(Wq, Wqt, HID_, QD);
  transpose_cast<<<dim3(KVD / 64, HID_ / 64), blk, 0, stream>>>(Wk, Wkvt, HID_, KVD);
  transpose_cast<<<dim3(KVD / 64, HID_ / 64), blk, 0, stream>>>(Wv, Wkvt + (size_t)KVD * HID_, HID_, KVD);
  transpose_cast<<<dim3(HID_ / 64, QD / 64), blk, 0, stream>>>(Wo, Wot, QD, HID_);
  cast_wg1<<<64, blk, 0, stream>>>(Wg1, Wg1t);
  // fused q|kv projection (MFMA, N=1536); k-relu deferred, v linear
  gemm_proj<<<dim3(NPROJ / 128, NTOK / 128), blk, 0, stream>>>(hb, Wqt, q, kv);
  // fused gate + decay cumsum (64 blocks, one per chunk)
  gate_cumsum<<<NTOK / CHUNK, blk, 0, stream>>>(hb, Wg1t, Wg2, bg2, bc);
  // chunked GLA (transposed M/S for MFMA b-fragments)
  chunk_kv<<<B_ * HKV_ * NC, blk, 0, stream>>>(kv, bc, Mt, E);
  state_scan<<<B_ * HKV_ * 16, blk, 0, stream>>>(Mt, E, Sbt);
  // per-chunk output + fused RMSNorm -> bf16
  gla_out<<<B_ * H_ * NC, blk, 0, stream>>>(q, kv, bc, Sbt, gw, obh);
  // output projection (MFMA)
  gemm_bf16_mfma<<<dim3(HID_ / 128, NTOK / 128), blk, 0, stream>>>(obh, Wot, out, NTOK, HID_, HID_);
}

// Round 12
// 210.642 us; speedup vs baseline: 7.1394x; 1.0827x over previous
//
#include <hip/hip_runtime.h>
#include <hip/hip_bf16.h>
#include <math.h>

#define B_    2
#define T_    2048
#define HID_  1024
#define H_    16
#define HKV_  4
#define D_    64
#define GLR_  16
#define NTOK  (B_*T_)        // 4096
#define KVD   (HKV_*D_)      // 256
#define KVSTR 512            // fused kv row stride (k:0..255, v:256..511)
#define QD    (H_*D_)        // 1024
#define NPROJ (QD+KVSTR)     // 1536 fused projection width
#define CHUNK 64
#define NC    (T_/CHUNK)     // 32
#define SCALE 0.125f         // D^-0.5
#define EPS_  1e-6f

typedef __attribute__((ext_vector_type(8))) short short8;
typedef __attribute__((ext_vector_type(4))) float f32x4;

__device__ __forceinline__ ushort f2b(float f) {
  __hip_bfloat16 h = __float2bfloat16(f);
  return *reinterpret_cast<ushort*>(&h);
}

// 16B async global->LDS copy (wave-uniform LDS base + lane*16 layout)
__device__ __forceinline__ void gload16(const ushort* g, ushort* l) {
  __builtin_amdgcn_global_load_lds(
      (const __attribute__((address_space(1))) unsigned int*)g,
      (__attribute__((address_space(3))) unsigned int*)l, 16, 0, 0);
}

// ---- one-shot staging: hb cast, Wg1t cast, 4 weight transposes (4800 blks) --
__global__ __launch_bounds__(256) void stage_all(const float* __restrict__ h,
                                                 const float* __restrict__ Wq,
                                                 const float* __restrict__ Wk,
                                                 const float* __restrict__ Wv,
                                                 const float* __restrict__ Wo,
                                                 const float* __restrict__ Wg1,
                                                 ushort* __restrict__ hb,
                                                 ushort* __restrict__ Wqt,
                                                 ushort* __restrict__ Wkvt,
                                                 ushort* __restrict__ Wot,
                                                 ushort* __restrict__ Wg1t) {
  __shared__ ushort tile[64][65];
  int bi = blockIdx.x;
  if (bi < 4096) {                       // h -> bf16, 4 elems/thread
    int i = bi * 256 + threadIdx.x;
    float4 v = *(const float4*)(h + (size_t)i * 4);
    ushort4 o; o.x = f2b(v.x); o.y = f2b(v.y); o.z = f2b(v.z); o.w = f2b(v.w);
    *(ushort4*)(hb + (size_t)i * 4) = o;
    return;
  }
  bi -= 4096;
  if (bi < 64) {                         // Wg1[1024,16] -> Wg1t[16][1024]
    int idx = bi * 256 + threadIdx.x;
    int kk = idx >> 4, n = idx & 15;
    Wg1t[(size_t)n * HID_ + kk] = f2b(Wg1[(size_t)kk * GLR_ + n]);
    return;
  }
  bi -= 64;
  const float* W; ushort* Wt; int K, N, nb_, kb_;
  if (bi < 256)      { W = Wq; Wt = Wqt;  K = HID_; N = QD;  nb_ = bi & 15; kb_ = bi >> 4; }
  else if (bi < 320) { bi -= 256; W = Wk; Wt = Wkvt; K = HID_; N = KVD; nb_ = bi & 3; kb_ = bi >> 2; }
  else if (bi < 384) { bi -= 320; W = Wv; Wt = Wkvt + (size_t)KVD * HID_; K = HID_; N = KVD; nb_ = bi & 3; kb_ = bi >> 2; }
  else               { bi -= 384; W = Wo; Wt = Wot;  K = QD;  N = HID_; nb_ = bi & 15; kb_ = bi >> 4; }
  int n0 = nb_ * 64, k0 = kb_ * 64;
  for (int idx = threadIdx.x; idx < 64 * 64; idx += 256) {
    int r = idx >> 6, c = idx & 63;                  // r: k-offset, c: n-offset
    tile[c][r] = f2b(W[(size_t)(k0 + r) * N + n0 + c]);
  }
  __syncthreads();
  for (int idx = threadIdx.x; idx < 64 * 64; idx += 256) {
    int r = idx >> 6, c = idx & 63;                  // r: n-offset, c: k-offset
    Wt[(size_t)(n0 + r) * K + k0 + c] = tile[r][c];
  }
}

// ---- fused projection GEMM: [q | kv] = hb @ [Wqt;Wkvt]^T, relu on q cols ---
// 128x128 tile, BK=32, 4 waves; global_load_lds width-16 staging, linear LDS.
__global__ __launch_bounds__(256) void gemm_proj(const ushort* __restrict__ A,
                                                 const ushort* __restrict__ Bt,
                                                 float* __restrict__ q,
                                                 float* __restrict__ kvo) {
  __shared__ ushort As[128][32];
  __shared__ ushort Bs[128][32];
  const int t = threadIdx.x;
  const int rowBase = blockIdx.y * 128, colBase = blockIdx.x * 128;
  const int lane = t & 63, w = t >> 6;
  const int wr = w >> 1, wc = w & 1;
  const int lrow = lane & 15, hi = lane >> 4;
  const int K = HID_;
  f32x4 acc[4][4];
#pragma unroll
  for (int mi = 0; mi < 4; ++mi)
#pragma unroll
    for (int ni = 0; ni < 4; ++ni) acc[mi][ni] = (f32x4){0.f, 0.f, 0.f, 0.f};

  for (int k0 = 0; k0 < K; k0 += 32) {
#pragma unroll
    for (int l = 0; l < 2; ++l) {
      int idx = t + (l << 8);                 // 0..511
      int row = idx >> 2, ch = (idx & 3) << 3;
      gload16(&A [(size_t)(rowBase + row) * K + k0 + ch], &As[0][0] + idx * 8);
      gload16(&Bt[(size_t)(colBase + row) * K + k0 + ch], &Bs[0][0] + idx * 8);
    }
    __syncthreads();
    short8 af[4], bf[4];
#pragma unroll
    for (int mi = 0; mi < 4; ++mi)
      af[mi] = *(const short8*)&As[wr * 64 + mi * 16 + lrow][hi * 8];
#pragma unroll
    for (int ni = 0; ni < 4; ++ni)
      bf[ni] = *(const short8*)&Bs[wc * 64 + ni * 16 + lrow][hi * 8];
#pragma unroll
    for (int mi = 0; mi < 4; ++mi)
#pragma unroll
      for (int ni = 0; ni < 4; ++ni)
        acc[mi][ni] = __builtin_amdgcn_mfma_f32_16x16x32_bf16(af[mi], bf[ni], acc[mi][ni], 0, 0, 0);
    __syncthreads();
  }
#pragma unroll
  for (int mi = 0; mi < 4; ++mi)
#pragma unroll
    for (int ni = 0; ni < 4; ++ni)
#pragma unroll
      for (int r = 0; r < 4; ++r) {
        int gm = rowBase + wr * 64 + mi * 16 + hi * 4 + r;
        int gn = colBase + wc * 64 + ni * 16 + lrow;
        float val = acc[mi][ni][r];
        if (gn < QD) q[(size_t)gm * QD + gn] = fmaxf(val, 0.f);
        else         kvo[(size_t)gm * KVSTR + gn - QD] = val;
      }
}

// -------- bf16 MFMA GEMM (Wo): C = A @ Bt^T, global_load_lds staging --------
__global__ __launch_bounds__(256) void gemm_bf16_mfma(const ushort* __restrict__ A,
                                                      const ushort* __restrict__ Bt,
                                                      float* __restrict__ C,
                                                      int M, int N, int K) {
  __shared__ ushort As[128][32];
  __shared__ ushort Bs[128][32];
  const int t = threadIdx.x;
  const int rowBase = blockIdx.y * 128, colBase = blockIdx.x * 128;
  const int lane = t & 63, w = t >> 6;
  const int wr = w >> 1, wc = w & 1;
  const int lrow = lane & 15, hi = lane >> 4;
  f32x4 acc[4][4];
#pragma unroll
  for (int mi = 0; mi < 4; ++mi)
#pragma unroll
    for (int ni = 0; ni < 4; ++ni) acc[mi][ni] = (f32x4){0.f, 0.f, 0.f, 0.f};

  for (int k0 = 0; k0 < K; k0 += 32) {
#pragma unroll
    for (int l = 0; l < 2; ++l) {
      int idx = t + (l << 8);
      int row = idx >> 2, ch = (idx & 3) << 3;
      gload16(&A [(size_t)(rowBase + row) * K + k0 + ch], &As[0][0] + idx * 8);
      gload16(&Bt[(size_t)(colBase + row) * K + k0 + ch], &Bs[0][0] + idx * 8);
    }
    __syncthreads();
    short8 af[4], bf[4];
#pragma unroll
    for (int mi = 0; mi < 4; ++mi)
      af[mi] = *(const short8*)&As[wr * 64 + mi * 16 + lrow][hi * 8];
#pragma unroll
    for (int ni = 0; ni < 4; ++ni)
      bf[ni] = *(const short8*)&Bs[wc * 64 + ni * 16 + lrow][hi * 8];
#pragma unroll
    for (int mi = 0; mi < 4; ++mi)
#pragma unroll
      for (int ni = 0; ni < 4; ++ni)
        acc[mi][ni] = __builtin_amdgcn_mfma_f32_16x16x32_bf16(af[mi], bf[ni], acc[mi][ni], 0, 0, 0);
    __syncthreads();
  }
#pragma unroll
  for (int mi = 0; mi < 4; ++mi)
#pragma unroll
    for (int ni = 0; ni < 4; ++ni)
#pragma unroll
      for (int r = 0; r < 4; ++r) {
        int gm = rowBase + wr * 64 + mi * 16 + hi * 4 + r;
        int gn = colBase + wc * 64 + ni * 16 + lrow;
        C[(size_t)gm * N + gn] = acc[mi][ni][r];
      }
}

// --- fused gate + decay cumsum: one block per 64-token chunk (64 blocks) ---
__global__ __launch_bounds__(256) void gate_cumsum(const ushort* __restrict__ hb,
                                                   const ushort* __restrict__ Wg1t,
                                                   const float* __restrict__ Wg2,
                                                   const float* __restrict__ bg2,
                                                   float* __restrict__ bc) {
  __shared__ float gts[CHUNK][GLR_ + 1];
  const int t = threadIdx.x, lane = t & 63, w = t >> 6;
  const int lrow = lane & 15, hi = lane >> 4;
  const int c0 = blockIdx.x * CHUNK;          // global token base
  const int b = c0 / T_, tloc = c0 % T_;
  {
    f32x4 acc = (f32x4){0.f, 0.f, 0.f, 0.f};
#pragma unroll
    for (int kk = 0; kk < 32; ++kk) {
      int k0 = kk * 32 + hi * 8;
      short8 a = *(const short8*)&hb[(size_t)(c0 + w * 16 + lrow) * HID_ + k0];
      short8 bf = *(const short8*)&Wg1t[(size_t)lrow * HID_ + k0];
      acc = __builtin_amdgcn_mfma_f32_16x16x32_bf16(a, bf, acc, 0, 0, 0);
    }
#pragma unroll
    for (int r = 0; r < 4; ++r) gts[w * 16 + hi * 4 + r][lrow] = acc[r];
  }
  __syncthreads();
  {
    const int c = t;                          // 0..255
    const int j = c >> 6, d = c & 63;
    const int gj = b * HKV_ + j;
    const float bias = bg2[c];
    float run = 0.f;
    size_t base = ((size_t)gj * T_ + tloc) * D_ + d;
    for (int tok = 0; tok < CHUNK; ++tok) {
      float acc2 = bias;
#pragma unroll
      for (int r = 0; r < GLR_; ++r) acc2 += gts[tok][r] * Wg2[r * KVD + c];
      float ls = fminf(acc2, 0.f) - log1pf(expf(-fabsf(acc2)));
      run += ls * (1.0f / 16.0f);
      bc[base + (size_t)tok * D_] = run;
    }
  }
}

// ---- per-chunk decayed K^T V, TRANSPOSED out: Mt[jv][i]; relu(k) here ----
__global__ __launch_bounds__(256) void chunk_kv(const float* __restrict__ kv,
                                                const float* __restrict__ bc,
                                                float* __restrict__ Mt,
                                                float* __restrict__ E) {
  __shared__ float ks[CHUNK][D_ + 1];
  __shared__ float vs[CHUNK][D_ + 1];
  __shared__ float blast[D_];
  int blk = blockIdx.x;             // gj*NC + c
  int c = blk % NC, gj = blk / NC;
  int b = gj >> 2, j = gj & 3;
  size_t kb = ((size_t)(b * T_ + c * CHUNK)) * KVSTR + j * D_;
  size_t bb = ((size_t)gj * T_ + c * CHUNK) * D_;
  if (threadIdx.x < D_) blast[threadIdx.x] = bc[bb + (size_t)(CHUNK - 1) * D_ + threadIdx.x];
  __syncthreads();
  for (int idx = threadIdx.x; idx < CHUNK * D_; idx += 256) {
    int t = idx >> 6, col = idx & 63;
    float bv = bc[bb + idx];
    ks[t][col] = fmaxf(kv[kb + (size_t)t * KVSTR + col], 0.f) * expf(blast[col] - bv);
    vs[t][col] = kv[kb + (size_t)t * KVSTR + 256 + col];
  }
  __syncthreads();
  int jv = threadIdx.x >> 2;            // v-dim row of Mt
  int i0 = (threadIdx.x & 3) * 16;      // k-dim col group
  float acc[16];
#pragma unroll
  for (int l = 0; l < 16; ++l) acc[l] = 0.f;
  for (int t = 0; t < CHUNK; ++t) {
    float vt_ = vs[t][jv];
#pragma unroll
    for (int l = 0; l < 16; ++l) acc[l] += vt_ * ks[t][i0 + l];
  }
  size_t mbase = (size_t)blk * D_ * D_ + (size_t)jv * D_ + i0;
#pragma unroll
  for (int l = 0; l < 16; ++l) Mt[mbase + l] = acc[l];
  if (threadIdx.x < D_) E[(size_t)blk * D_ + threadIdx.x] = expf(blast[threadIdx.x]);
}

// ---- elementwise inter-chunk scan on TRANSPOSED state: Sbt[gj][c][jv][i] ----
__global__ __launch_bounds__(256) void state_scan(const float* __restrict__ Mt,
                                                  const float* __restrict__ E,
                                                  float* __restrict__ Sbt) {
  int gj = blockIdx.x >> 4;
  int elem = ((blockIdx.x & 15) << 8) + threadIdx.x;   // jv*64 + i
  int i = elem & 63;                                   // k-dim index
  float S = 0.f;
#pragma unroll
  for (int c = 0; c < NC; ++c) {
    size_t base = ((size_t)gj * NC + c) * (D_ * D_) + elem;
    Sbt[base] = S;
    S = E[((size_t)gj * NC + c) * D_ + i] * S + Mt[base];
  }
}

// ---- per-chunk output via MFMA + fused RMSNorm (1024 blocks); bf16 out ----
__global__ __launch_bounds__(256) void gla_out(const float* __restrict__ q,
                                               const float* __restrict__ kv,
                                               const float* __restrict__ bc,
                                               const float* __restrict__ Sbt,
                                               const float* __restrict__ gw,
                                               ushort* __restrict__ obh) {
  __shared__ ushort qes[64][72];   // qe[t][d]  (stride 144B, 2-way free)
  __shared__ ushort kes[64][72];   // ke[s][d]
  __shared__ ushort vts[64][72];   // v^T[jv][s]
  __shared__ ushort sts[64][72];   // S^T[jv][d]
  __shared__ ushort Al [64][72];   // A[t][s] causal-masked, bf16
  int blk = blockIdx.x;                 // (b*H + h)*NC + c
  int c = blk % NC, bh = blk / NC;
  int b = bh / H_, h = bh % H_;
  int j = h >> 2, gj = b * HKV_ + j;
  size_t nb = (size_t)(b * T_ + c * CHUNK);
  size_t bb = ((size_t)gj * T_ + c * CHUNK) * D_;
  size_t sbase = ((size_t)gj * NC + c) * D_ * D_;
  const int t = threadIdx.x, lane = t & 63, w = t >> 6;
  const int lrow = lane & 15, hi = lane >> 4;
  for (int idx = t; idx < CHUNK * D_; idx += 256) {
    int tt = idx >> 6, col = idx & 63;
    float bv = bc[bb + idx];
    qes[tt][col] = f2b(q[(nb + tt) * QD + h * D_ + col] * expf(bv) * SCALE);
    kes[tt][col] = f2b(fmaxf(kv[(nb + tt) * KVSTR + j * D_ + col], 0.f) * expf(-bv));
    vts[col][tt] = f2b(kv[(nb + tt) * KVSTR + 256 + j * D_ + col]);
    sts[tt][col] = f2b(Sbt[sbase + idx]);   // tt=jv, col=i(d)
  }
  __syncthreads();
  {
    const int ti = w;
#pragma unroll
    for (int si = 0; si < 4; ++si) {
      f32x4 acc = (f32x4){0.f, 0.f, 0.f, 0.f};
      if (si <= ti) {
#pragma unroll
        for (int kk = 0; kk < 2; ++kk) {
          short8 a  = *(const short8*)&qes[ti * 16 + lrow][kk * 32 + hi * 8];
          short8 bf = *(const short8*)&kes[si * 16 + lrow][kk * 32 + hi * 8];
          acc = __builtin_amdgcn_mfma_f32_16x16x32_bf16(a, bf, acc, 0, 0, 0);
        }
      }
#pragma unroll
      for (int r = 0; r < 4; ++r) {
        int grow = ti * 16 + hi * 4 + r, gcol = si * 16 + lrow;
        Al[grow][gcol] = f2b(gcol <= grow ? acc[r] : 0.f);
      }
    }
  }
  __syncthreads();
  {
    float o[4][4];                       // [ni][r]
#pragma unroll
    for (int ni = 0; ni < 4; ++ni) {
      f32x4 acc = (f32x4){0.f, 0.f, 0.f, 0.f};
#pragma unroll
      for (int kk = 0; kk < 2; ++kk) {
        short8 a  = *(const short8*)&qes[w * 16 + lrow][kk * 32 + hi * 8];
        short8 bf = *(const short8*)&sts[ni * 16 + lrow][kk * 32 + hi * 8];
        acc = __builtin_amdgcn_mfma_f32_16x16x32_bf16(a, bf, acc, 0, 0, 0);
      }
#pragma unroll
      for (int kk = 0; kk < 2; ++kk) {
        short8 a  = *(const short8*)&Al[w * 16 + lrow][kk * 32 + hi * 8];
        short8 bf = *(const short8*)&vts[ni * 16 + lrow][kk * 32 + hi * 8];
        acc = __builtin_amdgcn_mfma_f32_16x16x32_bf16(a, bf, acc, 0, 0, 0);
      }
#pragma unroll
      for (int r = 0; r < 4; ++r) o[ni][r] = acc[r];
    }
#pragma unroll
    for (int r = 0; r < 4; ++r) {
      float ss = o[0][r] * o[0][r] + o[1][r] * o[1][r]
               + o[2][r] * o[2][r] + o[3][r] * o[3][r];
      ss += __shfl_xor(ss, 1, 64);
      ss += __shfl_xor(ss, 2, 64);
      ss += __shfl_xor(ss, 4, 64);
      ss += __shfl_xor(ss, 8, 64);
      float inv = rsqrtf(ss * (1.0f / D_) + EPS_);
      size_t rowoff = (nb + w * 16 + hi * 4 + r) * QD + h * D_;
#pragma unroll
      for (int ni = 0; ni < 4; ++ni) {
        int d = ni * 16 + lrow;
        obh[rowoff + d] = f2b(gw[d] * o[ni][r] * inv);
      }
    }
  }
}

extern "C" void kernel_launch(void* const* d_in, const int* in_sizes, int n_in,
                              void* d_out, int out_size, void* d_ws, size_t ws_size,
                              hipStream_t stream) {
  const float* h   = (const float*)d_in[0];
  const float* Wq  = (const float*)d_in[1];
  const float* Wk  = (const float*)d_in[2];
  const float* Wv  = (const float*)d_in[3];
  const float* Wo  = (const float*)d_in[4];
  const float* Wg1 = (const float*)d_in[5];
  const float* Wg2 = (const float*)d_in[6];
  const float* bg2 = (const float*)d_in[7];
  const float* gw  = (const float*)d_in[8];
  float* out = (float*)d_out;

  float* q   = (float*)d_ws;                          // [4096,1024]
  float* kv  = q  + (size_t)NTOK * QD;                // [4096,512]
  float* bc  = kv + (size_t)NTOK * KVSTR;             // [8,2048,64]
  float* Sbt = bc + (size_t)B_ * HKV_ * T_ * D_;      // [8,32,64,64]
  float* Mt  = Sbt + (size_t)B_ * HKV_ * NC * D_ * D_;// [8,32,64,64]
  float* E   = Mt + (size_t)B_ * HKV_ * NC * D_ * D_; // [8,32,64]
  ushort* hb   = (ushort*)(E + (size_t)B_ * HKV_ * NC * D_); // [4096,1024] bf16 (reused as obh)
  ushort* Wqt  = hb   + (size_t)NTOK * HID_;          // [1024,1024] } contiguous ->
  ushort* Wkvt = Wqt  + (size_t)HID_ * QD;            // [512,1024]  } Bt with N=1536
  ushort* Wot  = Wkvt + (size_t)KVSTR * HID_;         // [1024,1024]
  ushort* Wg1t = Wot  + (size_t)HID_ * QD;            // [16,1024]
  ushort* obh = hb;

  dim3 blk(256);
  // one-shot bf16 staging (h cast + all weight transposes/casts)
  stage_all<<<4800, blk, 0, stream>>>(h, Wq, Wk, Wv, Wo, Wg1, hb, Wqt, Wkvt, Wot, Wg1t);
  // fused q|kv projection (MFMA + global_load_lds, N=1536)
  gemm_proj<<<dim3(NPROJ / 128, NTOK / 128), blk, 0, stream>>>(hb, Wqt, q, kv);
  // fused gate + decay cumsum (64 blocks, one per chunk)
  gate_cumsum<<<NTOK / CHUNK, blk, 0, stream>>>(hb, Wg1t, Wg2, bg2, bc);
  // chunked GLA (transposed M/S for MFMA b-fragments)
  chunk_kv<<<B_ * HKV_ * NC, blk, 0, stream>>>(kv, bc, Mt, E);
  state_scan<<<B_ * HKV_ * 16, blk, 0, stream>>>(Mt, E, Sbt);
  // per-chunk output + fused RMSNorm -> bf16
  gla_out<<<B_ * H_ * NC, blk, 0, stream>>>(q, kv, bc, Sbt, gw, obh);
  // output projection (MFMA + global_load_lds)
  gemm_bf16_mfma<<<dim3(HID_ / 128, NTOK / 128), blk, 0, stream>>>(obh, Wot, out, NTOK, HID_, HID_);
}

// Round 13
// 200.821 us; speedup vs baseline: 7.4885x; 1.0489x over previous
//
#include <hip/hip_runtime.h>
#include <hip/hip_bf16.h>
#include <math.h>

#define B_    2
#define T_    2048
#define HID_  1024
#define H_    16
#define HKV_  4
#define D_    64
#define GLR_  16
#define NTOK  (B_*T_)        // 4096
#define KVD   (HKV_*D_)      // 256
#define KVSTR 512            // fused kv row stride (k:0..255, v:256..511)
#define QD    (H_*D_)        // 1024
#define NPROJ (QD+KVSTR)     // 1536 fused projection width
#define CHUNK 64
#define NC    (T_/CHUNK)     // 32
#define SCALE 0.125f         // D^-0.5
#define EPS_  1e-6f

typedef __attribute__((ext_vector_type(8))) short short8;
typedef __attribute__((ext_vector_type(4))) float f32x4;

__device__ __forceinline__ ushort f2b(float f) {
  __hip_bfloat16 h = __float2bfloat16(f);
  return *reinterpret_cast<ushort*>(&h);
}
__device__ __forceinline__ float b2f(ushort u) {
  __hip_bfloat16 h = *reinterpret_cast<__hip_bfloat16*>(&u);
  return __bfloat162float(h);
}

// 16B async global->LDS copy (wave-uniform LDS base + lane*16 layout)
__device__ __forceinline__ void gload16(const ushort* g, ushort* l) {
  __builtin_amdgcn_global_load_lds(
      (const __attribute__((address_space(1))) unsigned int*)g,
      (__attribute__((address_space(3))) unsigned int*)l, 16, 0, 0);
}

// ---- one-shot staging: hb cast, Wg1t cast, 4 weight transposes (4800 blks) --
__global__ __launch_bounds__(256) void stage_all(const float* __restrict__ h,
                                                 const float* __restrict__ Wq,
                                                 const float* __restrict__ Wk,
                                                 const float* __restrict__ Wv,
                                                 const float* __restrict__ Wo,
                                                 const float* __restrict__ Wg1,
                                                 ushort* __restrict__ hb,
                                                 ushort* __restrict__ Wqt,
                                                 ushort* __restrict__ Wkvt,
                                                 ushort* __restrict__ Wot,
                                                 ushort* __restrict__ Wg1t) {
  __shared__ ushort tile[64][65];
  int bi = blockIdx.x;
  if (bi < 4096) {                       // h -> bf16, 4 elems/thread
    int i = bi * 256 + threadIdx.x;
    float4 v = *(const float4*)(h + (size_t)i * 4);
    ushort4 o; o.x = f2b(v.x); o.y = f2b(v.y); o.z = f2b(v.z); o.w = f2b(v.w);
    *(ushort4*)(hb + (size_t)i * 4) = o;
    return;
  }
  bi -= 4096;
  if (bi < 64) {                         // Wg1[1024,16] -> Wg1t[16][1024]
    int idx = bi * 256 + threadIdx.x;
    int kk = idx >> 4, n = idx & 15;
    Wg1t[(size_t)n * HID_ + kk] = f2b(Wg1[(size_t)kk * GLR_ + n]);
    return;
  }
  bi -= 64;
  const float* W; ushort* Wt; int K, N, nb_, kb_;
  if (bi < 256)      { W = Wq; Wt = Wqt;  K = HID_; N = QD;  nb_ = bi & 15; kb_ = bi >> 4; }
  else if (bi < 320) { bi -= 256; W = Wk; Wt = Wkvt; K = HID_; N = KVD; nb_ = bi & 3; kb_ = bi >> 2; }
  else if (bi < 384) { bi -= 320; W = Wv; Wt = Wkvt + (size_t)KVD * HID_; K = HID_; N = KVD; nb_ = bi & 3; kb_ = bi >> 2; }
  else               { bi -= 384; W = Wo; Wt = Wot;  K = QD;  N = HID_; nb_ = bi & 15; kb_ = bi >> 4; }
  int n0 = nb_ * 64, k0 = kb_ * 64;
  for (int idx = threadIdx.x; idx < 64 * 64; idx += 256) {
    int r = idx >> 6, c = idx & 63;                  // r: k-offset, c: n-offset
    tile[c][r] = f2b(W[(size_t)(k0 + r) * N + n0 + c]);
  }
  __syncthreads();
  for (int idx = threadIdx.x; idx < 64 * 64; idx += 256) {
    int r = idx >> 6, c = idx & 63;                  // r: n-offset, c: k-offset
    Wt[(size_t)(n0 + r) * K + k0 + c] = tile[r][c];
  }
}

// ---- fused projection GEMM: [q | kv] = hb @ [Wqt;Wkvt]^T, bf16 out ----
// 128x128 tile, BK=32, 4 waves; global_load_lds width-16 staging, linear LDS.
__global__ __launch_bounds__(256) void gemm_proj(const ushort* __restrict__ A,
                                                 const ushort* __restrict__ Bt,
                                                 ushort* __restrict__ qb,
                                                 ushort* __restrict__ kvb) {
  __shared__ ushort As[128][32];
  __shared__ ushort Bs[128][32];
  const int t = threadIdx.x;
  const int rowBase = blockIdx.y * 128, colBase = blockIdx.x * 128;
  const int lane = t & 63, w = t >> 6;
  const int wr = w >> 1, wc = w & 1;
  const int lrow = lane & 15, hi = lane >> 4;
  const int K = HID_;
  f32x4 acc[4][4];
#pragma unroll
  for (int mi = 0; mi < 4; ++mi)
#pragma unroll
    for (int ni = 0; ni < 4; ++ni) acc[mi][ni] = (f32x4){0.f, 0.f, 0.f, 0.f};

  for (int k0 = 0; k0 < K; k0 += 32) {
#pragma unroll
    for (int l = 0; l < 2; ++l) {
      int idx = t + (l << 8);                 // 0..511
      int row = idx >> 2, ch = (idx & 3) << 3;
      gload16(&A [(size_t)(rowBase + row) * K + k0 + ch], &As[0][0] + idx * 8);
      gload16(&Bt[(size_t)(colBase + row) * K + k0 + ch], &Bs[0][0] + idx * 8);
    }
    __syncthreads();
    short8 af[4], bf[4];
#pragma unroll
    for (int mi = 0; mi < 4; ++mi)
      af[mi] = *(const short8*)&As[wr * 64 + mi * 16 + lrow][hi * 8];
#pragma unroll
    for (int ni = 0; ni < 4; ++ni)
      bf[ni] = *(const short8*)&Bs[wc * 64 + ni * 16 + lrow][hi * 8];
#pragma unroll
    for (int mi = 0; mi < 4; ++mi)
#pragma unroll
      for (int ni = 0; ni < 4; ++ni)
        acc[mi][ni] = __builtin_amdgcn_mfma_f32_16x16x32_bf16(af[mi], bf[ni], acc[mi][ni], 0, 0, 0);
    __syncthreads();
  }
#pragma unroll
  for (int mi = 0; mi < 4; ++mi)
#pragma unroll
    for (int ni = 0; ni < 4; ++ni)
#pragma unroll
      for (int r = 0; r < 4; ++r) {
        int gm = rowBase + wr * 64 + mi * 16 + hi * 4 + r;
        int gn = colBase + wc * 64 + ni * 16 + lrow;
        float val = acc[mi][ni][r];
        if (gn < QD) qb[(size_t)gm * QD + gn] = f2b(fmaxf(val, 0.f));
        else         kvb[(size_t)gm * KVSTR + gn - QD] = f2b(val);
      }
}

// -------- bf16 MFMA GEMM (Wo): C = A @ Bt^T, global_load_lds staging --------
__global__ __launch_bounds__(256) void gemm_bf16_mfma(const ushort* __restrict__ A,
                                                      const ushort* __restrict__ Bt,
                                                      float* __restrict__ C,
                                                      int M, int N, int K) {
  __shared__ ushort As[128][32];
  __shared__ ushort Bs[128][32];
  const int t = threadIdx.x;
  const int rowBase = blockIdx.y * 128, colBase = blockIdx.x * 128;
  const int lane = t & 63, w = t >> 6;
  const int wr = w >> 1, wc = w & 1;
  const int lrow = lane & 15, hi = lane >> 4;
  f32x4 acc[4][4];
#pragma unroll
  for (int mi = 0; mi < 4; ++mi)
#pragma unroll
    for (int ni = 0; ni < 4; ++ni) acc[mi][ni] = (f32x4){0.f, 0.f, 0.f, 0.f};

  for (int k0 = 0; k0 < K; k0 += 32) {
#pragma unroll
    for (int l = 0; l < 2; ++l) {
      int idx = t + (l << 8);
      int row = idx >> 2, ch = (idx & 3) << 3;
      gload16(&A [(size_t)(rowBase + row) * K + k0 + ch], &As[0][0] + idx * 8);
      gload16(&Bt[(size_t)(colBase + row) * K + k0 + ch], &Bs[0][0] + idx * 8);
    }
    __syncthreads();
    short8 af[4], bf[4];
#pragma unroll
    for (int mi = 0; mi < 4; ++mi)
      af[mi] = *(const short8*)&As[wr * 64 + mi * 16 + lrow][hi * 8];
#pragma unroll
    for (int ni = 0; ni < 4; ++ni)
      bf[ni] = *(const short8*)&Bs[wc * 64 + ni * 16 + lrow][hi * 8];
#pragma unroll
    for (int mi = 0; mi < 4; ++mi)
#pragma unroll
      for (int ni = 0; ni < 4; ++ni)
        acc[mi][ni] = __builtin_amdgcn_mfma_f32_16x16x32_bf16(af[mi], bf[ni], acc[mi][ni], 0, 0, 0);
    __syncthreads();
  }
#pragma unroll
  for (int mi = 0; mi < 4; ++mi)
#pragma unroll
    for (int ni = 0; ni < 4; ++ni)
#pragma unroll
      for (int r = 0; r < 4; ++r) {
        int gm = rowBase + wr * 64 + mi * 16 + hi * 4 + r;
        int gn = colBase + wc * 64 + ni * 16 + lrow;
        C[(size_t)gm * N + gn] = acc[mi][ni][r];
      }
}

// --- fused gate + decay cumsum: one block per 64-token chunk (64 blocks) ---
__global__ __launch_bounds__(256) void gate_cumsum(const ushort* __restrict__ hb,
                                                   const ushort* __restrict__ Wg1t,
                                                   const float* __restrict__ Wg2,
                                                   const float* __restrict__ bg2,
                                                   float* __restrict__ bc) {
  __shared__ float gts[CHUNK][GLR_ + 1];
  const int t = threadIdx.x, lane = t & 63, w = t >> 6;
  const int lrow = lane & 15, hi = lane >> 4;
  const int c0 = blockIdx.x * CHUNK;          // global token base
  const int b = c0 / T_, tloc = c0 % T_;
  {
    f32x4 acc = (f32x4){0.f, 0.f, 0.f, 0.f};
#pragma unroll
    for (int kk = 0; kk < 32; ++kk) {
      int k0 = kk * 32 + hi * 8;
      short8 a = *(const short8*)&hb[(size_t)(c0 + w * 16 + lrow) * HID_ + k0];
      short8 bf = *(const short8*)&Wg1t[(size_t)lrow * HID_ + k0];
      acc = __builtin_amdgcn_mfma_f32_16x16x32_bf16(a, bf, acc, 0, 0, 0);
    }
#pragma unroll
    for (int r = 0; r < 4; ++r) gts[w * 16 + hi * 4 + r][lrow] = acc[r];
  }
  __syncthreads();
  {
    const int c = t;                          // 0..255
    const int j = c >> 6, d = c & 63;
    const int gj = b * HKV_ + j;
    const float bias = bg2[c];
    float run = 0.f;
    size_t base = ((size_t)gj * T_ + tloc) * D_ + d;
    for (int tok = 0; tok < CHUNK; ++tok) {
      float acc2 = bias;
#pragma unroll
      for (int r = 0; r < GLR_; ++r) acc2 += gts[tok][r] * Wg2[r * KVD + c];
      float ls = fminf(acc2, 0.f) - log1pf(expf(-fabsf(acc2)));
      run += ls * (1.0f / 16.0f);
      bc[base + (size_t)tok * D_] = run;
    }
  }
}

// ---- per-chunk decayed K^T V via MFMA: Mt[jv][i] = sum_t v[t][jv]*k'[t][i] --
// Stage v^T and k'^T bf16 in LDS; 4 waves x (4 n-tiles x 2 K-slices) MFMA.
__global__ __launch_bounds__(256) void chunk_kv(const ushort* __restrict__ kvb,
                                                const float* __restrict__ bc,
                                                float* __restrict__ Mt,
                                                float* __restrict__ E) {
  __shared__ ushort vts[64][72];   // v^T[jv][t]
  __shared__ ushort kts[64][72];   // k'^T[i][t]
  __shared__ float blast[D_];
  int blk = blockIdx.x;             // gj*NC + c
  int c = blk % NC, gj = blk / NC;
  int b = gj >> 2, j = gj & 3;
  size_t kb = ((size_t)(b * T_ + c * CHUNK)) * KVSTR + j * D_;
  size_t bb = ((size_t)gj * T_ + c * CHUNK) * D_;
  const int t = threadIdx.x, lane = t & 63, w = t >> 6;
  const int lrow = lane & 15, hi = lane >> 4;
  if (t < D_) blast[t] = bc[bb + (size_t)(CHUNK - 1) * D_ + t];
  __syncthreads();
  for (int idx = t; idx < CHUNK * D_; idx += 256) {
    int tt = idx >> 6, col = idx & 63;
    float bv = bc[bb + idx];
    kts[col][tt] = f2b(fmaxf(b2f(kvb[kb + (size_t)tt * KVSTR + col]), 0.f) * expf(blast[col] - bv));
    vts[col][tt] = kvb[kb + (size_t)tt * KVSTR + 256 + col];
  }
  __syncthreads();
  // wave w: Mt rows [w*16, w*16+16) (jv), all 64 cols (i)
#pragma unroll
  for (int ni = 0; ni < 4; ++ni) {
    f32x4 acc = (f32x4){0.f, 0.f, 0.f, 0.f};
#pragma unroll
    for (int kk = 0; kk < 2; ++kk) {
      short8 a  = *(const short8*)&vts[w * 16 + lrow][kk * 32 + hi * 8];
      short8 bf = *(const short8*)&kts[ni * 16 + lrow][kk * 32 + hi * 8];
      acc = __builtin_amdgcn_mfma_f32_16x16x32_bf16(a, bf, acc, 0, 0, 0);
    }
#pragma unroll
    for (int r = 0; r < 4; ++r)
      Mt[(size_t)blk * D_ * D_ + (size_t)(w * 16 + hi * 4 + r) * D_ + ni * 16 + lrow] = acc[r];
  }
  if (t < D_) E[(size_t)blk * D_ + t] = expf(blast[t]);
}

// ---- elementwise inter-chunk scan on TRANSPOSED state: Sbt[gj][c][jv][i] ----
__global__ __launch_bounds__(256) void state_scan(const float* __restrict__ Mt,
                                                  const float* __restrict__ E,
                                                  float* __restrict__ Sbt) {
  int gj = blockIdx.x >> 4;
  int elem = ((blockIdx.x & 15) << 8) + threadIdx.x;   // jv*64 + i
  int i = elem & 63;                                   // k-dim index
  float S = 0.f;
#pragma unroll
  for (int c = 0; c < NC; ++c) {
    size_t base = ((size_t)gj * NC + c) * (D_ * D_) + elem;
    Sbt[base] = S;
    S = E[((size_t)gj * NC + c) * D_ + i] * S + Mt[base];
  }
}

// ---- per-chunk output via MFMA + fused RMSNorm (1024 blocks); bf16 out ----
__global__ __launch_bounds__(256) void gla_out(const ushort* __restrict__ qb,
                                               const ushort* __restrict__ kvb,
                                               const float* __restrict__ bc,
                                               const float* __restrict__ Sbt,
                                               const float* __restrict__ gw,
                                               ushort* __restrict__ obh) {
  __shared__ ushort qes[64][72];   // qe[t][d]  (stride 144B, 2-way free)
  __shared__ ushort kes[64][72];   // ke[s][d]
  __shared__ ushort vts[64][72];   // v^T[jv][s]
  __shared__ ushort sts[64][72];   // S^T[jv][d]
  __shared__ ushort Al [64][72];   // A[t][s] causal-masked, bf16
  int blk = blockIdx.x;                 // (b*H + h)*NC + c
  int c = blk % NC, bh = blk / NC;
  int b = bh / H_, h = bh % H_;
  int j = h >> 2, gj = b * HKV_ + j;
  size_t nb = (size_t)(b * T_ + c * CHUNK);
  size_t bb = ((size_t)gj * T_ + c * CHUNK) * D_;
  size_t sbase = ((size_t)gj * NC + c) * D_ * D_;
  const int t = threadIdx.x, lane = t & 63, w = t >> 6;
  const int lrow = lane & 15, hi = lane >> 4;
  for (int idx = t; idx < CHUNK * D_; idx += 256) {
    int tt = idx >> 6, col = idx & 63;
    float bv = bc[bb + idx];
    qes[tt][col] = f2b(b2f(qb[(nb + tt) * QD + h * D_ + col]) * expf(bv) * SCALE);
    kes[tt][col] = f2b(fmaxf(b2f(kvb[(nb + tt) * KVSTR + j * D_ + col]), 0.f) * expf(-bv));
    vts[col][tt] = kvb[(nb + tt) * KVSTR + 256 + j * D_ + col];
    sts[tt][col] = f2b(Sbt[sbase + idx]);   // tt=jv, col=i(d)
  }
  __syncthreads();
  {
    const int ti = w;
#pragma unroll
    for (int si = 0; si < 4; ++si) {
      f32x4 acc = (f32x4){0.f, 0.f, 0.f, 0.f};
      if (si <= ti) {
#pragma unroll
        for (int kk = 0; kk < 2; ++kk) {
          short8 a  = *(const short8*)&qes[ti * 16 + lrow][kk * 32 + hi * 8];
          short8 bf = *(const short8*)&kes[si * 16 + lrow][kk * 32 + hi * 8];
          acc = __builtin_amdgcn_mfma_f32_16x16x32_bf16(a, bf, acc, 0, 0, 0);
        }
      }
#pragma unroll
      for (int r = 0; r < 4; ++r) {
        int grow = ti * 16 + hi * 4 + r, gcol = si * 16 + lrow;
        Al[grow][gcol] = f2b(gcol <= grow ? acc[r] : 0.f);
      }
    }
  }
  __syncthreads();
  {
    float o[4][4];                       // [ni][r]
#pragma unroll
    for (int ni = 0; ni < 4; ++ni) {
      f32x4 acc = (f32x4){0.f, 0.f, 0.f, 0.f};
#pragma unroll
      for (int kk = 0; kk < 2; ++kk) {
        short8 a  = *(const short8*)&qes[w * 16 + lrow][kk * 32 + hi * 8];
        short8 bf = *(const short8*)&sts[ni * 16 + lrow][kk * 32 + hi * 8];
        acc = __builtin_amdgcn_mfma_f32_16x16x32_bf16(a, bf, acc, 0, 0, 0);
      }
#pragma unroll
      for (int kk = 0; kk < 2; ++kk) {
        short8 a  = *(const short8*)&Al[w * 16 + lrow][kk * 32 + hi * 8];
        short8 bf = *(const short8*)&vts[ni * 16 + lrow][kk * 32 + hi * 8];
        acc = __builtin_amdgcn_mfma_f32_16x16x32_bf16(a, bf, acc, 0, 0, 0);
      }
#pragma unroll
      for (int r = 0; r < 4; ++r) o[ni][r] = acc[r];
    }
#pragma unroll
    for (int r = 0; r < 4; ++r) {
      float ss = o[0][r] * o[0][r] + o[1][r] * o[1][r]
               + o[2][r] * o[2][r] + o[3][r] * o[3][r];
      ss += __shfl_xor(ss, 1, 64);
      ss += __shfl_xor(ss, 2, 64);
      ss += __shfl_xor(ss, 4, 64);
      ss += __shfl_xor(ss, 8, 64);
      float inv = rsqrtf(ss * (1.0f / D_) + EPS_);
      size_t rowoff = (nb + w * 16 + hi * 4 + r) * QD + h * D_;
#pragma unroll
      for (int ni = 0; ni < 4; ++ni) {
        int d = ni * 16 + lrow;
        obh[rowoff + d] = f2b(gw[d] * o[ni][r] * inv);
      }
    }
  }
}

extern "C" void kernel_launch(void* const* d_in, const int* in_sizes, int n_in,
                              void* d_out, int out_size, void* d_ws, size_t ws_size,
                              hipStream_t stream) {
  const float* h   = (const float*)d_in[0];
  const float* Wq  = (const float*)d_in[1];
  const float* Wk  = (const float*)d_in[2];
  const float* Wv  = (const float*)d_in[3];
  const float* Wo  = (const float*)d_in[4];
  const float* Wg1 = (const float*)d_in[5];
  const float* Wg2 = (const float*)d_in[6];
  const float* bg2 = (const float*)d_in[7];
  const float* gw  = (const float*)d_in[8];
  float* out = (float*)d_out;

  ushort* qb   = (ushort*)d_ws;                       // [4096,1024] bf16
  ushort* kvb  = qb   + (size_t)NTOK * QD;            // [4096,512]  bf16
  ushort* hb   = kvb  + (size_t)NTOK * KVSTR;         // [4096,1024] bf16 (reused as obh)
  ushort* Wqt  = hb   + (size_t)NTOK * HID_;          // [1024,1024] } contiguous ->
  ushort* Wkvt = Wqt  + (size_t)HID_ * QD;            // [512,1024]  } Bt with N=1536
  ushort* Wot  = Wkvt + (size_t)KVSTR * HID_;         // [1024,1024]
  ushort* Wg1t = Wot  + (size_t)HID_ * QD;            // [16,1024]
  float* bc  = (float*)(Wg1t + (size_t)GLR_ * HID_);  // [8,2048,64]
  float* Sbt = bc + (size_t)B_ * HKV_ * T_ * D_;      // [8,32,64,64]
  float* Mt  = Sbt + (size_t)B_ * HKV_ * NC * D_ * D_;// [8,32,64,64]
  float* E   = Mt + (size_t)B_ * HKV_ * NC * D_ * D_; // [8,32,64]
  ushort* obh = hb;

  dim3 blk(256);
  // one-shot bf16 staging (h cast + all weight transposes/casts)
  stage_all<<<4800, blk, 0, stream>>>(h, Wq, Wk, Wv, Wo, Wg1, hb, Wqt, Wkvt, Wot, Wg1t);
  // fused q|kv projection (MFMA + global_load_lds, N=1536, bf16 out)
  gemm_proj<<<dim3(NPROJ / 128, NTOK / 128), blk, 0, stream>>>(hb, Wqt, qb, kvb);
  // fused gate + decay cumsum (64 blocks, one per chunk)
  gate_cumsum<<<NTOK / CHUNK, blk, 0, stream>>>(hb, Wg1t, Wg2, bg2, bc);
  // chunked GLA (MFMA chunk_kv; transposed M/S)
  chunk_kv<<<B_ * HKV_ * NC, blk, 0, stream>>>(kvb, bc, Mt, E);
  state_scan<<<B_ * HKV_ * 16, blk, 0, stream>>>(Mt, E, Sbt);
  // per-chunk output + fused RMSNorm -> bf16
  gla_out<<<B_ * H_ * NC, blk, 0, stream>>>(qb, kvb, bc, Sbt, gw, obh);
  // output projection (MFMA + global_load_lds)
  gemm_bf16_mfma<<<dim3(HID_ / 128, NTOK / 128), blk, 0, stream>>>(obh, Wot, out, NTOK, HID_, HID_);
}

// Round 17
// 177.965 us; speedup vs baseline: 8.4503x; 1.1284x over previous
//
#include <hip/hip_runtime.h>
#include <hip/hip_bf16.h>
#include <math.h>

#define B_    2
#define T_    2048
#define HID_  1024
#define H_    16
#define HKV_  4
#define D_    64
#define GLR_  16
#define NTOK  (B_*T_)        // 4096
#define KVD   (HKV_*D_)      // 256
#define KVSTR 512            // fused kv row stride (k:0..255, v:256..511)
#define QD    (H_*D_)        // 1024
#define NPROJ (QD+KVSTR)     // 1536 fused projection width
#define CHUNK 64
#define NC    (T_/CHUNK)     // 32
#define SCALE 0.125f         // D^-0.5
#define EPS_  1e-6f
#define NPROJBLK ((NPROJ/128)*(NTOK/64))   // 768 proj blocks

typedef __attribute__((ext_vector_type(8))) short short8;
typedef __attribute__((ext_vector_type(4))) float f32x4;

__device__ __forceinline__ ushort f2b(float f) {
  __hip_bfloat16 h = __float2bfloat16(f);
  return *reinterpret_cast<ushort*>(&h);
}
__device__ __forceinline__ float b2f(ushort u) {
  __hip_bfloat16 h = *reinterpret_cast<__hip_bfloat16*>(&u);
  return __bfloat162float(h);
}

// 16B async global->LDS copy (wave-uniform LDS base + lane*16 layout)
__device__ __forceinline__ void gload16(const ushort* g, ushort* l) {
  __builtin_amdgcn_global_load_lds(
      (const __attribute__((address_space(1))) unsigned int*)g,
      (__attribute__((address_space(3))) unsigned int*)l, 16, 0, 0);
}

// ---- one-shot staging: hb cast, Wg1t cast, 4 weight transposes (4800 blks) --
__global__ __launch_bounds__(256) void stage_all(const float* __restrict__ h,
                                                 const float* __restrict__ Wq,
                                                 const float* __restrict__ Wk,
                                                 const float* __restrict__ Wv,
                                                 const float* __restrict__ Wo,
                                                 const float* __restrict__ Wg1,
                                                 ushort* __restrict__ hb,
                                                 ushort* __restrict__ Wqt,
                                                 ushort* __restrict__ Wkvt,
                                                 ushort* __restrict__ Wot,
                                                 ushort* __restrict__ Wg1t) {
  __shared__ ushort tile[64][65];
  int bi = blockIdx.x;
  if (bi < 4096) {                       // h -> bf16, 4 elems/thread
    int i = bi * 256 + threadIdx.x;
    float4 v = *(const float4*)(h + (size_t)i * 4);
    ushort4 o; o.x = f2b(v.x); o.y = f2b(v.y); o.z = f2b(v.z); o.w = f2b(v.w);
    *(ushort4*)(hb + (size_t)i * 4) = o;
    return;
  }
  bi -= 4096;
  if (bi < 64) {                         // Wg1[1024,16] -> Wg1t[16][1024]
    int idx = bi * 256 + threadIdx.x;
    int kk = idx >> 4, n = idx & 15;
    Wg1t[(size_t)n * HID_ + kk] = f2b(Wg1[(size_t)kk * GLR_ + n]);
    return;
  }
  bi -= 64;
  const float* W; ushort* Wt; int K, N, nb_, kb_;
  if (bi < 256)      { W = Wq; Wt = Wqt;  K = HID_; N = QD;  nb_ = bi & 15; kb_ = bi >> 4; }
  else if (bi < 320) { bi -= 256; W = Wk; Wt = Wkvt; K = HID_; N = KVD; nb_ = bi & 3; kb_ = bi >> 2; }
  else if (bi < 384) { bi -= 320; W = Wv; Wt = Wkvt + (size_t)KVD * HID_; K = HID_; N = KVD; nb_ = bi & 3; kb_ = bi >> 2; }
  else               { bi -= 384; W = Wo; Wt = Wot;  K = QD;  N = HID_; nb_ = bi & 15; kb_ = bi >> 4; }
  int n0 = nb_ * 64, k0 = kb_ * 64;
  for (int idx = threadIdx.x; idx < 64 * 64; idx += 256) {
    int r = idx >> 6, c = idx & 63;                  // r: k-offset, c: n-offset
    tile[c][r] = f2b(W[(size_t)(k0 + r) * N + n0 + c]);
  }
  __syncthreads();
  for (int idx = threadIdx.x; idx < 64 * 64; idx += 256) {
    int r = idx >> 6, c = idx & 63;                  // r: n-offset, c: k-offset
    Wt[(size_t)(n0 + r) * K + k0 + c] = tile[r][c];
  }
}

// ---- merged dispatch: 768 proj blocks (64x128 tile) + 64 gate blocks ----
// proj: [q|kv] = hb @ [Wqt;Wkvt]^T, bf16 out, relu on q cols.
// gate: gt = hb@Wg1t^T (MFMA), bc = cumsum(logsigmoid(gt@Wg2+bg2)/16).
__global__ __launch_bounds__(256) void proj_gate(const ushort* __restrict__ A,
                                                 const ushort* __restrict__ Bt,
                                                 const ushort* __restrict__ Wg1t,
                                                 const float* __restrict__ Wg2,
                                                 const float* __restrict__ bg2,
                                                 ushort* __restrict__ qb,
                                                 ushort* __restrict__ kvb,
                                                 float* __restrict__ bc) {
  __shared__ ushort As[64][32];
  __shared__ ushort Bs[128][32];
  __shared__ float gts[CHUNK][GLR_ + 1];
  const int t = threadIdx.x, lane = t & 63, w = t >> 6;
  const int lrow = lane & 15, hi = lane >> 4;
  int bi = blockIdx.x;
  if (bi < NPROJBLK) {
    // ---------------- projection GEMM: BM=64, BN=128, BK=32 ----------------
    const int bx = bi % (NPROJ / 128), by = bi / (NPROJ / 128);
    const int rowBase = by * 64, colBase = bx * 128;
    const int wm = w >> 1, wn = w & 1;
    f32x4 acc[2][4];
#pragma unroll
    for (int mi = 0; mi < 2; ++mi)
#pragma unroll
      for (int ni = 0; ni < 4; ++ni) acc[mi][ni] = (f32x4){0.f, 0.f, 0.f, 0.f};
    for (int k0 = 0; k0 < HID_; k0 += 32) {
      gload16(&A[(size_t)(rowBase + (t >> 2)) * HID_ + k0 + ((t & 3) << 3)],
              &As[0][0] + t * 8);
#pragma unroll
      for (int l = 0; l < 2; ++l) {
        int idx = t + (l << 8);
        gload16(&Bt[(size_t)(colBase + (idx >> 2)) * HID_ + k0 + ((idx & 3) << 3)],
                &Bs[0][0] + idx * 8);
      }
      __syncthreads();
      short8 af[2], bf[4];
#pragma unroll
      for (int mi = 0; mi < 2; ++mi)
        af[mi] = *(const short8*)&As[wm * 32 + mi * 16 + lrow][hi * 8];
#pragma unroll
      for (int ni = 0; ni < 4; ++ni)
        bf[ni] = *(const short8*)&Bs[wn * 64 + ni * 16 + lrow][hi * 8];
#pragma unroll
      for (int mi = 0; mi < 2; ++mi)
#pragma unroll
        for (int ni = 0; ni < 4; ++ni)
          acc[mi][ni] = __builtin_amdgcn_mfma_f32_16x16x32_bf16(af[mi], bf[ni], acc[mi][ni], 0, 0, 0);
      __syncthreads();
    }
#pragma unroll
    for (int mi = 0; mi < 2; ++mi)
#pragma unroll
      for (int ni = 0; ni < 4; ++ni)
#pragma unroll
        for (int r = 0; r < 4; ++r) {
          int gm = rowBase + wm * 32 + mi * 16 + hi * 4 + r;
          int gn = colBase + wn * 64 + ni * 16 + lrow;
          float val = acc[mi][ni][r];
          if (gn < QD) qb[(size_t)gm * QD + gn] = f2b(fmaxf(val, 0.f));
          else         kvb[(size_t)gm * KVSTR + gn - QD] = f2b(val);
        }
    return;
  }
  // ------------------------- gate + cumsum branch --------------------------
  bi -= NPROJBLK;                              // 0..63, one per 64-token chunk
  const int c0 = bi * CHUNK;
  const int b = c0 / T_, tloc = c0 % T_;
  {
    f32x4 acc = (f32x4){0.f, 0.f, 0.f, 0.f};
#pragma unroll
    for (int kk = 0; kk < 32; ++kk) {
      int k0 = kk * 32 + hi * 8;
      short8 a = *(const short8*)&A[(size_t)(c0 + w * 16 + lrow) * HID_ + k0];
      short8 bf = *(const short8*)&Wg1t[(size_t)lrow * HID_ + k0];
      acc = __builtin_amdgcn_mfma_f32_16x16x32_bf16(a, bf, acc, 0, 0, 0);
    }
#pragma unroll
    for (int r = 0; r < 4; ++r) gts[w * 16 + hi * 4 + r][lrow] = acc[r];
  }
  __syncthreads();
  {
    const int c = t;                          // 0..255
    const int j = c >> 6, d = c & 63;
    const int gj = b * HKV_ + j;
    const float bias = bg2[c];
    float run = 0.f;
    size_t base = ((size_t)gj * T_ + tloc) * D_ + d;
    for (int tok = 0; tok < CHUNK; ++tok) {
      float acc2 = bias;
#pragma unroll
      for (int r = 0; r < GLR_; ++r) acc2 += gts[tok][r] * Wg2[r * KVD + c];
      float ls = fminf(acc2, 0.f) - log1pf(expf(-fabsf(acc2)));
      run += ls * (1.0f / 16.0f);
      bc[base + (size_t)tok * D_] = run;
    }
  }
}

// ------- Wo GEMM: C[M,N] = A @ Bt^T, BM=64 BN=128 BK=32, f32 out -------
__global__ __launch_bounds__(256) void gemm_wo(const ushort* __restrict__ A,
                                               const ushort* __restrict__ Bt,
                                               float* __restrict__ C) {
  __shared__ ushort As[64][32];
  __shared__ ushort Bs[128][32];
  const int t = threadIdx.x, lane = t & 63, w = t >> 6;
  const int lrow = lane & 15, hi = lane >> 4;
  const int rowBase = blockIdx.y * 64, colBase = blockIdx.x * 128;
  const int wm = w >> 1, wn = w & 1;
  const int N = HID_, K = HID_;
  f32x4 acc[2][4];
#pragma unroll
  for (int mi = 0; mi < 2; ++mi)
#pragma unroll
    for (int ni = 0; ni < 4; ++ni) acc[mi][ni] = (f32x4){0.f, 0.f, 0.f, 0.f};
  for (int k0 = 0; k0 < K; k0 += 32) {
    gload16(&A[(size_t)(rowBase + (t >> 2)) * K + k0 + ((t & 3) << 3)],
            &As[0][0] + t * 8);
#pragma unroll
    for (int l = 0; l < 2; ++l) {
      int idx = t + (l << 8);
      gload16(&Bt[(size_t)(colBase + (idx >> 2)) * K + k0 + ((idx & 3) << 3)],
              &Bs[0][0] + idx * 8);
    }
    __syncthreads();
    short8 af[2], bf[4];
#pragma unroll
    for (int mi = 0; mi < 2; ++mi)
      af[mi] = *(const short8*)&As[wm * 32 + mi * 16 + lrow][hi * 8];
#pragma unroll
    for (int ni = 0; ni < 4; ++ni)
      bf[ni] = *(const short8*)&Bs[wn * 64 + ni * 16 + lrow][hi * 8];
#pragma unroll
    for (int mi = 0; mi < 2; ++mi)
#pragma unroll
      for (int ni = 0; ni < 4; ++ni)
        acc[mi][ni] = __builtin_amdgcn_mfma_f32_16x16x32_bf16(af[mi], bf[ni], acc[mi][ni], 0, 0, 0);
    __syncthreads();
  }
#pragma unroll
  for (int mi = 0; mi < 2; ++mi)
#pragma unroll
    for (int ni = 0; ni < 4; ++ni)
#pragma unroll
      for (int r = 0; r < 4; ++r) {
        int gm = rowBase + wm * 32 + mi * 16 + hi * 4 + r;
        int gn = colBase + wn * 64 + ni * 16 + lrow;
        C[(size_t)gm * N + gn] = acc[mi][ni][r];
      }
}

// ---- per-chunk decayed K^T V via MFMA: Mt[jv][i] = sum_t v[t][jv]*k'[t][i] --
__global__ __launch_bounds__(256) void chunk_kv(const ushort* __restrict__ kvb,
                                                const float* __restrict__ bc,
                                                float* __restrict__ Mt,
                                                float* __restrict__ E) {
  __shared__ ushort vts[64][72];   // v^T[jv][t]
  __shared__ ushort kts[64][72];   // k'^T[i][t]
  __shared__ float blast[D_];
  int blk = blockIdx.x;             // gj*NC + c
  int c = blk % NC, gj = blk / NC;
  int b = gj >> 2, j = gj & 3;
  size_t kb = ((size_t)(b * T_ + c * CHUNK)) * KVSTR + j * D_;
  size_t bb = ((size_t)gj * T_ + c * CHUNK) * D_;
  const int t = threadIdx.x, lane = t & 63, w = t >> 6;
  const int lrow = lane & 15, hi = lane >> 4;
  if (t < D_) blast[t] = bc[bb + (size_t)(CHUNK - 1) * D_ + t];
  __syncthreads();
  for (int idx = t; idx < CHUNK * D_; idx += 256) {
    int tt = idx >> 6, col = idx & 63;
    float bv = bc[bb + idx];
    kts[col][tt] = f2b(fmaxf(b2f(kvb[kb + (size_t)tt * KVSTR + col]), 0.f) * expf(blast[col] - bv));
    vts[col][tt] = kvb[kb + (size_t)tt * KVSTR + 256 + col];
  }
  __syncthreads();
#pragma unroll
  for (int ni = 0; ni < 4; ++ni) {
    f32x4 acc = (f32x4){0.f, 0.f, 0.f, 0.f};
#pragma unroll
    for (int kk = 0; kk < 2; ++kk) {
      short8 a  = *(const short8*)&vts[w * 16 + lrow][kk * 32 + hi * 8];
      short8 bf = *(const short8*)&kts[ni * 16 + lrow][kk * 32 + hi * 8];
      acc = __builtin_amdgcn_mfma_f32_16x16x32_bf16(a, bf, acc, 0, 0, 0);
    }
#pragma unroll
    for (int r = 0; r < 4; ++r)
      Mt[(size_t)blk * D_ * D_ + (size_t)(w * 16 + hi * 4 + r) * D_ + ni * 16 + lrow] = acc[r];
  }
  if (t < D_) E[(size_t)blk * D_ + t] = expf(blast[t]);
}

// -- inter-chunk scan (f32 state in-reg), bf16 Sbt out: Sbtb[gj][c][jv][i] --
__global__ __launch_bounds__(256) void state_scan(const float* __restrict__ Mt,
                                                  const float* __restrict__ E,
                                                  ushort* __restrict__ Sbtb) {
  int gj = blockIdx.x >> 4;
  int elem = ((blockIdx.x & 15) << 8) + threadIdx.x;   // jv*64 + i
  int i = elem & 63;                                   // k-dim index
  float S = 0.f;
#pragma unroll
  for (int c = 0; c < NC; ++c) {
    size_t base = ((size_t)gj * NC + c) * (D_ * D_) + elem;
    Sbtb[base] = f2b(S);
    S = E[((size_t)gj * NC + c) * D_ + i] * S + Mt[base];
  }
}

// ---- per-chunk output via MFMA + fused RMSNorm (1024 blocks); bf16 out ----
__global__ __launch_bounds__(256) void gla_out(const ushort* __restrict__ qb,
                                               const ushort* __restrict__ kvb,
                                               const float* __restrict__ bc,
                                               const ushort* __restrict__ Sbtb,
                                               const float* __restrict__ gw,
                                               ushort* __restrict__ obh) {
  __shared__ ushort qes[64][72];   // qe[t][d]  (stride 144B, 2-way free)
  __shared__ ushort kes[64][72];   // ke[s][d]
  __shared__ ushort vts[64][72];   // v^T[jv][s]
  __shared__ ushort sts[64][72];   // S^T[jv][d]
  __shared__ ushort Al [64][72];   // A[t][s] causal-masked, bf16
  int blk = blockIdx.x;                 // (b*H + h)*NC + c
  int c = blk % NC, bh = blk / NC;
  int b = bh / H_, h = bh % H_;
  int j = h >> 2, gj = b * HKV_ + j;
  size_t nb = (size_t)(b * T_ + c * CHUNK);
  size_t bb = ((size_t)gj * T_ + c * CHUNK) * D_;
  size_t sbase = ((size_t)gj * NC + c) * D_ * D_;
  const int t = threadIdx.x, lane = t & 63, w = t >> 6;
  const int lrow = lane & 15, hi = lane >> 4;
  for (int idx = t; idx < CHUNK * D_; idx += 256) {
    int tt = idx >> 6, col = idx & 63;
    float bv = bc[bb + idx];
    qes[tt][col] = f2b(b2f(qb[(nb + tt) * QD + h * D_ + col]) * expf(bv) * SCALE);
    kes[tt][col] = f2b(fmaxf(b2f(kvb[(nb + tt) * KVSTR + j * D_ + col]), 0.f) * expf(-bv));
    vts[col][tt] = kvb[(nb + tt) * KVSTR + 256 + j * D_ + col];
    sts[tt][col] = Sbtb[sbase + idx];   // tt=jv, col=i(d), raw bf16 copy
  }
  __syncthreads();
  {
    const int ti = w;
#pragma unroll
    for (int si = 0; si < 4; ++si) {
      f32x4 acc = (f32x4){0.f, 0.f, 0.f, 0.f};
      if (si <= ti) {
#pragma unroll
        for (int kk = 0; kk < 2; ++kk) {
          short8 a  = *(const short8*)&qes[ti * 16 + lrow][kk * 32 + hi * 8];
          short8 bf = *(const short8*)&kes[si * 16 + lrow][kk * 32 + hi * 8];
          acc = __builtin_amdgcn_mfma_f32_16x16x32_bf16(a, bf, acc, 0, 0, 0);
        }
      }
#pragma unroll
      for (int r = 0; r < 4; ++r) {
        int grow = ti * 16 + hi * 4 + r, gcol = si * 16 + lrow;
        Al[grow][gcol] = f2b(gcol <= grow ? acc[r] : 0.f);
      }
    }
  }
  __syncthreads();
  {
    float o[4][4];                       // [ni][r]
#pragma unroll
    for (int ni = 0; ni < 4; ++ni) {
      f32x4 acc = (f32x4){0.f, 0.f, 0.f, 0.f};
#pragma unroll
      for (int kk = 0; kk < 2; ++kk) {
        short8 a  = *(const short8*)&qes[w * 16 + lrow][kk * 32 + hi * 8];
        short8 bf = *(const short8*)&sts[ni * 16 + lrow][kk * 32 + hi * 8];
        acc = __builtin_amdgcn_mfma_f32_16x16x32_bf16(a, bf, acc, 0, 0, 0);
      }
#pragma unroll
      for (int kk = 0; kk < 2; ++kk) {
        short8 a  = *(const short8*)&Al[w * 16 + lrow][kk * 32 + hi * 8];
        short8 bf = *(const short8*)&vts[ni * 16 + lrow][kk * 32 + hi * 8];
        acc = __builtin_amdgcn_mfma_f32_16x16x32_bf16(a, bf, acc, 0, 0, 0);
      }
#pragma unroll
      for (int r = 0; r < 4; ++r) o[ni][r] = acc[r];
    }
#pragma unroll
    for (int r = 0; r < 4; ++r) {
      float ss = o[0][r] * o[0][r] + o[1][r] * o[1][r]
               + o[2][r] * o[2][r] + o[3][r] * o[3][r];
      ss += __shfl_xor(ss, 1, 64);
      ss += __shfl_xor(ss, 2, 64);
      ss += __shfl_xor(ss, 4, 64);
      ss += __shfl_xor(ss, 8, 64);
      float inv = rsqrtf(ss * (1.0f / D_) + EPS_);
      size_t rowoff = (nb + w * 16 + hi * 4 + r) * QD + h * D_;
#pragma unroll
      for (int ni = 0; ni < 4; ++ni) {
        int d = ni * 16 + lrow;
        obh[rowoff + d] = f2b(gw[d] * o[ni][r] * inv);
      }
    }
  }
}

extern "C" void kernel_launch(void* const* d_in, const int* in_sizes, int n_in,
                              void* d_out, int out_size, void* d_ws, size_t ws_size,
                              hipStream_t stream) {
  const float* h   = (const float*)d_in[0];
  const float* Wq  = (const float*)d_in[1];
  const float* Wk  = (const float*)d_in[2];
  const float* Wv  = (const float*)d_in[3];
  const float* Wo  = (const float*)d_in[4];
  const float* Wg1 = (const float*)d_in[5];
  const float* Wg2 = (const float*)d_in[6];
  const float* bg2 = (const float*)d_in[7];
  const float* gw  = (const float*)d_in[8];
  float* out = (float*)d_out;

  ushort* qb   = (ushort*)d_ws;                       // [4096,1024] bf16
  ushort* kvb  = qb   + (size_t)NTOK * QD;            // [4096,512]  bf16
  ushort* hb   = kvb  + (size_t)NTOK * KVSTR;         // [4096,1024] bf16 (reused as obh)
  ushort* Wqt  = hb   + (size_t)NTOK * HID_;          // [1024,1024] } contiguous ->
  ushort* Wkvt = Wqt  + (size_t)HID_ * QD;            // [512,1024]  } Bt with N=1536
  ushort* Wot  = Wkvt + (size_t)KVSTR * HID_;         // [1024,1024]
  ushort* Wg1t = Wot  + (size_t)HID_ * QD;            // [16,1024]
  ushort* Sbtb = Wg1t + (size_t)GLR_ * HID_;          // [8,32,64,64] bf16
  float* bc  = (float*)(Sbtb + (size_t)B_ * HKV_ * NC * D_ * D_); // [8,2048,64]
  float* Mt  = bc + (size_t)B_ * HKV_ * T_ * D_;      // [8,32,64,64]
  float* E   = Mt + (size_t)B_ * HKV_ * NC * D_ * D_; // [8,32,64]
  ushort* obh = hb;

  dim3 blk(256);
  // one-shot bf16 staging (h cast + all weight transposes/casts)
  stage_all<<<4800, blk, 0, stream>>>(h, Wq, Wk, Wv, Wo, Wg1, hb, Wqt, Wkvt, Wot, Wg1t);
  // merged: q|kv projection (768 blocks, 64x128 tile) + gate/cumsum (64 blocks)
  proj_gate<<<NPROJBLK + NTOK / CHUNK, blk, 0, stream>>>(hb, Wqt, Wg1t, Wg2, bg2, qb, kvb, bc);
  // chunked GLA (MFMA chunk_kv; transposed M/S)
  chunk_kv<<<B_ * HKV_ * NC, blk, 0, stream>>>(kvb, bc, Mt, E);
  state_scan<<<B_ * HKV_ * 16, blk, 0, stream>>>(Mt, E, Sbtb);
  // per-chunk output + fused RMSNorm -> bf16
  gla_out<<<B_ * H_ * NC, blk, 0, stream>>>(qb, kvb, bc, Sbtb, gw, obh);
  // output projection (MFMA + global_load_lds, 64x128 tile)
  gemm_wo<<<dim3(HID_ / 128, NTOK / 64), blk, 0, stream>>>(obh, Wot, out);
}